// Round 1
// baseline (719.412 us; speedup 1.0000x reference)
//
#include <hip/hip_runtime.h>
#include <cstdint>
#include <cstddef>

// ---------------- degree histogram ----------------
__global__ void deg_kernel(const int* __restrict__ dst, int E, int* __restrict__ deg) {
  int e = blockIdx.x * blockDim.x + threadIdx.x;
  if (e < E) atomicAdd(&deg[dst[e]], 1);
}

__global__ void inv_deg_kernel(const int* __restrict__ deg, float* __restrict__ inv, int N) {
  int i = blockIdx.x * blockDim.x + threadIdx.x;
  if (i < N) inv[i] = 1.0f / fmaxf((float)deg[i], 1.0f);
}

// ---------------- single-block exclusive scan (N ~ 50001 elems) ----------------
__global__ __launch_bounds__(1024) void scan_kernel(const int* __restrict__ deg,
                                                    int* __restrict__ offsets, int n) {
  __shared__ int buf[1024];
  __shared__ int carry_s;
  int tid = threadIdx.x;
  if (tid == 0) carry_s = 0;
  __syncthreads();
  for (int base = 0; base < n; base += 1024) {
    int i = base + tid;
    int v = (i < n) ? deg[i] : 0;
    buf[tid] = v;
    __syncthreads();
    #pragma unroll
    for (int off = 1; off < 1024; off <<= 1) {
      int t = (tid >= off) ? buf[tid - off] : 0;
      __syncthreads();
      buf[tid] += t;
      __syncthreads();
    }
    int incl = buf[tid];
    int total = buf[1023];
    int carry = carry_s;
    if (i < n) offsets[i] = carry + incl - v;
    __syncthreads();            // everyone done reading carry_s & buf
    if (tid == 0) carry_s = carry + total;
    __syncthreads();
  }
  if (tid == 0) offsets[n] = carry_s;
}

// ---------------- scatter edges into CSR order ----------------
__global__ void scatter_kernel(const int* __restrict__ src, const int* __restrict__ dst, int E,
                               const int* __restrict__ offsets, int* __restrict__ cursor,
                               int* __restrict__ ssrc) {
  int e = blockIdx.x * blockDim.x + threadIdx.x;
  if (e < E) {
    int d = dst[e];
    int pos = offsets[d] + atomicAdd(&cursor[d], 1);
    ssrc[pos] = src[e];
  }
}

// ---------------- per-node mean aggregation: one block (D threads) per node ----------------
__global__ void agg_kernel(const float* __restrict__ feat, int D,
                           const int* __restrict__ offsets, const int* __restrict__ ssrc,
                           const float* __restrict__ inv_deg, float* __restrict__ out) {
  int n = blockIdx.x;
  int d = threadIdx.x;
  int s = offsets[n], e = offsets[n + 1];
  float acc = 0.0f;
  for (int i = s; i < e; ++i) {
    int sn = ssrc[i];
    acc += feat[(size_t)sn * D + d];
  }
  out[(size_t)n * D + d] = acc * inv_deg[n];
}

// ---------------- tiled fp32 GEMM with concatenated A = [A0 | A1] ----------------
// C[M,N] = concat(A0[M,K0], A1[M,K-K0]) @ W[K,N] + bias, optional relu.
// Block: 256 threads, 64x64 C tile, each thread 4x4, BK=16.
#define BM 64
#define BN 64
#define BK 16
__global__ __launch_bounds__(256) void gemm_cat(const float* __restrict__ A0,
                                                const float* __restrict__ A1,
                                                int K0, int K, int M, int N,
                                                const float* __restrict__ W,
                                                const float* __restrict__ bias,
                                                float* __restrict__ C, int relu) {
  __shared__ float As[BK][BM];  // A^T tile
  __shared__ float Ws[BK][BN];
  int bm = blockIdx.x * BM;
  int bn = blockIdx.y * BN;
  int tid = threadIdx.x;
  int tcol = tid & 15;   // N direction
  int trow = tid >> 4;   // M direction
  int K1 = K - K0;

  float acc[4][4];
  #pragma unroll
  for (int i = 0; i < 4; ++i)
    #pragma unroll
    for (int j = 0; j < 4; ++j) acc[i][j] = 0.0f;

  int ar = tid >> 2;             // 0..63 (A tile row)
  int ac = (tid & 3) << 2;       // 0,4,8,12 (A tile col, float4)
  int wr = tid >> 4;             // 0..15 (W tile row)
  int wc = (tid & 15) << 2;      // 0..60 (W tile col, float4)
  int gm = bm + ar;

  for (int kt = 0; kt < K; kt += BK) {
    float4 av = make_float4(0.f, 0.f, 0.f, 0.f);
    if (gm < M) {
      int gk = kt + ac;  // K0 is a multiple of 16, so a float4 never crosses A0/A1
      const float* srcp = (gk < K0) ? (A0 + (size_t)gm * K0 + gk)
                                    : (A1 + (size_t)gm * K1 + (gk - K0));
      av = *(const float4*)srcp;
    }
    As[ac + 0][ar] = av.x;
    As[ac + 1][ar] = av.y;
    As[ac + 2][ar] = av.z;
    As[ac + 3][ar] = av.w;
    *(float4*)&Ws[wr][wc] = *(const float4*)(W + (size_t)(kt + wr) * N + bn + wc);
    __syncthreads();
    #pragma unroll
    for (int k = 0; k < BK; ++k) {
      float4 a = *(float4*)&As[k][trow * 4];
      float4 w = *(float4*)&Ws[k][tcol * 4];
      acc[0][0] += a.x * w.x; acc[0][1] += a.x * w.y; acc[0][2] += a.x * w.z; acc[0][3] += a.x * w.w;
      acc[1][0] += a.y * w.x; acc[1][1] += a.y * w.y; acc[1][2] += a.y * w.z; acc[1][3] += a.y * w.w;
      acc[2][0] += a.z * w.x; acc[2][1] += a.z * w.y; acc[2][2] += a.z * w.z; acc[2][3] += a.z * w.w;
      acc[3][0] += a.w * w.x; acc[3][1] += a.w * w.y; acc[3][2] += a.w * w.z; acc[3][3] += a.w * w.w;
    }
    __syncthreads();
  }

  #pragma unroll
  for (int i = 0; i < 4; ++i) {
    int row = bm + trow * 4 + i;
    if (row < M) {
      #pragma unroll
      for (int j = 0; j < 4; ++j) {
        int col = bn + tcol * 4 + j;
        float v = acc[i][j] + bias[col];
        if (relu) v = fmaxf(v, 0.0f);
        C[(size_t)row * N + col] = v;
      }
    }
  }
}

// ---------------- log_softmax over rows of 128, in place ----------------
__global__ __launch_bounds__(128) void logsoftmax_kernel(float* __restrict__ y, int D) {
  int row = blockIdx.x;
  int tid = threadIdx.x;
  float v = y[(size_t)row * D + tid];
  __shared__ float sm[2], ss[2];
  float m = v;
  #pragma unroll
  for (int off = 1; off < 64; off <<= 1) m = fmaxf(m, __shfl_xor(m, off, 64));
  if ((tid & 63) == 0) sm[tid >> 6] = m;
  __syncthreads();
  m = fmaxf(sm[0], sm[1]);
  float ev = expf(v - m);
  float s = ev;
  #pragma unroll
  for (int off = 1; off < 64; off <<= 1) s += __shfl_xor(s, off, 64);
  if ((tid & 63) == 0) ss[tid >> 6] = s;
  __syncthreads();
  s = ss[0] + ss[1];
  y[(size_t)row * D + tid] = v - m - logf(s);
}

extern "C" void kernel_launch(void* const* d_in, const int* in_sizes, int n_in,
                              void* d_out, int out_size, void* d_ws, size_t ws_size,
                              hipStream_t stream) {
  const float* x        = (const float*)d_in[0];
  const int*   edge_src = (const int*)d_in[1];
  const int*   edge_dst = (const int*)d_in[2];
  const float* W1       = (const float*)d_in[3];
  const float* b1       = (const float*)d_in[4];
  const float* W2       = (const float*)d_in[5];
  const float* b2       = (const float*)d_in[6];
  float* out = (float*)d_out;

  const int D_IN = 128, D_HID = 256, D_OUT = 128;
  const int N = in_sizes[0] / D_IN;
  const int E = in_sizes[1];

  // ---- workspace layout ----
  char* ws = (char*)d_ws;
  size_t p = 0;
  auto take = [&](size_t bytes) -> size_t {
    size_t r = p;
    p += (bytes + 255) & ~(size_t)255;
    return r;
  };
  size_t deg_off  = take((size_t)N * 4);
  size_t cur_off  = take((size_t)N * 4);
  size_t inv_off  = take((size_t)N * 4);
  size_t offs_off = take((size_t)(N + 1) * 4);
  size_t ssrc_off = take((size_t)E * 4);
  size_t agg1_off = take((size_t)N * D_IN * 4);
  size_t h_off    = take((size_t)N * D_HID * 4);
  size_t agg2_off = take((size_t)N * D_HID * 4);
  (void)ws_size;

  int*   deg     = (int*)(ws + deg_off);
  int*   cursor  = (int*)(ws + cur_off);
  float* inv_deg = (float*)(ws + inv_off);
  int*   offsets = (int*)(ws + offs_off);
  int*   ssrc    = (int*)(ws + ssrc_off);
  float* agg1    = (float*)(ws + agg1_off);
  float* h       = (float*)(ws + h_off);
  float* agg2    = (float*)(ws + agg2_off);

  hipMemsetAsync(deg, 0, (size_t)N * 4, stream);
  hipMemsetAsync(cursor, 0, (size_t)N * 4, stream);

  int eb = (E + 255) / 256;
  deg_kernel<<<eb, 256, 0, stream>>>(edge_dst, E, deg);
  scan_kernel<<<1, 1024, 0, stream>>>(deg, offsets, N);
  inv_deg_kernel<<<(N + 255) / 256, 256, 0, stream>>>(deg, inv_deg, N);
  scatter_kernel<<<eb, 256, 0, stream>>>(edge_src, edge_dst, E, offsets, cursor, ssrc);

  // layer 1
  agg_kernel<<<N, D_IN, 0, stream>>>(x, D_IN, offsets, ssrc, inv_deg, agg1);
  {
    dim3 grid((N + BM - 1) / BM, D_HID / BN);
    gemm_cat<<<grid, 256, 0, stream>>>(x, agg1, D_IN, 2 * D_IN, N, D_HID, W1, b1, h, 1);
  }

  // layer 2
  agg_kernel<<<N, D_HID, 0, stream>>>(h, D_HID, offsets, ssrc, inv_deg, agg2);
  {
    dim3 grid((N + BM - 1) / BM, D_OUT / BN);
    gemm_cat<<<grid, 256, 0, stream>>>(h, agg2, D_HID, 2 * D_HID, N, D_OUT, W2, b2, out, 0);
  }

  logsoftmax_kernel<<<N, D_OUT, 0, stream>>>(out, D_OUT);
}

// Round 2
// 354.042 us; speedup vs baseline: 2.0320x; 2.0320x over previous
//
#include <hip/hip_runtime.h>
#include <cstdint>
#include <cstddef>

typedef __attribute__((ext_vector_type(8))) short bf16x8;
typedef __attribute__((ext_vector_type(4))) float f32x4;

__device__ inline short bf16_rne(float f) {
  unsigned u = __builtin_bit_cast(unsigned, f);
  u += 0x7fff + ((u >> 16) & 1);
  return (short)(u >> 16);
}

__device__ inline void async_copy16(const void* g, void* l) {
  __builtin_amdgcn_global_load_lds((const __attribute__((address_space(1))) void*)g,
                                   (__attribute__((address_space(3))) void*)l, 16, 0, 0);
}

// ---------------- degree histogram ----------------
__global__ void deg_kernel(const int* __restrict__ dst, int E, int* __restrict__ deg) {
  int e = blockIdx.x * blockDim.x + threadIdx.x;
  if (e < E) atomicAdd(&deg[dst[e]], 1);
}

__global__ void inv_deg_kernel(const int* __restrict__ deg, float* __restrict__ inv, int N) {
  int i = blockIdx.x * blockDim.x + threadIdx.x;
  if (i < N) inv[i] = 1.0f / fmaxf((float)deg[i], 1.0f);
}

// ---------------- hierarchical scan: per-block scan ----------------
__global__ __launch_bounds__(1024) void scan1_kernel(const int* __restrict__ deg,
                                                     int* __restrict__ offsets,
                                                     int* __restrict__ part, int n) {
  __shared__ int buf[1024];
  int tid = threadIdx.x;
  int i = blockIdx.x * 1024 + tid;
  int v = (i < n) ? deg[i] : 0;
  buf[tid] = v;
  __syncthreads();
  #pragma unroll
  for (int off = 1; off < 1024; off <<= 1) {
    int t = (tid >= off) ? buf[tid - off] : 0;
    __syncthreads();
    buf[tid] += t;
    __syncthreads();
  }
  if (i < n) offsets[i] = buf[tid] - v;  // exclusive within block
  if (tid == 1023) part[blockIdx.x] = buf[1023];
}

// ---------------- scan partials (B <= 64) with one wave ----------------
__global__ __launch_bounds__(64) void scan2_kernel(int* __restrict__ part,
                                                   int* __restrict__ offsets, int n, int B) {
  int lane = threadIdx.x;
  int v = (lane < B) ? part[lane] : 0;
  int orig = v;
  #pragma unroll
  for (int off = 1; off < 64; off <<= 1) {
    int t = __shfl_up(v, off, 64);
    if (lane >= off) v += t;
  }
  if (lane < B) part[lane] = v - orig;   // exclusive scan of partials
  if (lane == 63) offsets[n] = v;        // grand total
}

__global__ __launch_bounds__(1024) void scan3_kernel(int* __restrict__ offsets,
                                                     const int* __restrict__ part, int n) {
  int i = blockIdx.x * 1024 + threadIdx.x;
  if (i < n) offsets[i] += part[blockIdx.x];
}

// ---------------- scatter edges into CSR order ----------------
__global__ void scatter_kernel(const int* __restrict__ src, const int* __restrict__ dst, int E,
                               const int* __restrict__ offsets, int* __restrict__ cursor,
                               int* __restrict__ ssrc) {
  int e = blockIdx.x * blockDim.x + threadIdx.x;
  if (e < E) {
    int d = dst[e];
    int pos = offsets[d] + atomicAdd(&cursor[d], 1);
    ssrc[pos] = src[e];
  }
}

// ---------------- convert x -> bf16 into A1 left half ----------------
__global__ void convert_x_kernel(const float* __restrict__ x, short* __restrict__ A1, int total) {
  int idx = blockIdx.x * blockDim.x + threadIdx.x;
  if (idx < total) {
    int n = idx >> 7, d = idx & 127;
    A1[(size_t)n * 256 + d] = bf16_rne(x[idx]);
  }
}

// ---------------- layer-1 aggregation: mean of x over in-edges -> bf16 A1 right half ----
__global__ __launch_bounds__(128) void agg1_kernel(const float* __restrict__ x,
                                                   const int* __restrict__ offsets,
                                                   const int* __restrict__ ssrc,
                                                   const float* __restrict__ inv_deg,
                                                   short* __restrict__ A1) {
  int n = blockIdx.x;
  int d = threadIdx.x;
  int s = offsets[n], e = offsets[n + 1];
  float a0 = 0.f, a1 = 0.f, a2 = 0.f, a3 = 0.f;
  int i = s;
  for (; i + 4 <= e; i += 4) {
    int s0 = ssrc[i], s1 = ssrc[i + 1], s2 = ssrc[i + 2], s3 = ssrc[i + 3];
    a0 += x[(size_t)s0 * 128 + d];
    a1 += x[(size_t)s1 * 128 + d];
    a2 += x[(size_t)s2 * 128 + d];
    a3 += x[(size_t)s3 * 128 + d];
  }
  for (; i < e; ++i) a0 += x[(size_t)ssrc[i] * 128 + d];
  float r = (a0 + a1 + a2 + a3) * inv_deg[n];
  A1[(size_t)n * 256 + 128 + d] = bf16_rne(r);
}

// ---------------- weight pack into frag-ordered bf16 layout ----------------
// Bp[((kb*16+nt)*64+L)*8+j] = W[k= kb*32+(L>>4)*8+j][n= nt*16+(L&15)]
// mode 0: W is [256,256] row-major. mode 1: W is W2 [512,128]; cols 0..127 from
// rows 0..255 (top), cols 128..255 from rows 256..511 (bottom).
__global__ void pack_w_kernel(const float* __restrict__ W, short* __restrict__ Bp, int mode) {
  int idx = blockIdx.x * 256 + threadIdx.x;  // 65536 total
  int j = idx & 7;
  int L = (idx >> 3) & 63;
  int nt = (idx >> 9) & 15;
  int kb = idx >> 13;
  int k = kb * 32 + (L >> 4) * 8 + j;
  int n = nt * 16 + (L & 15);
  float v;
  if (mode == 0) v = W[(size_t)k * 256 + n];
  else v = (n < 128) ? W[(size_t)k * 128 + n] : W[(size_t)(256 + k) * 128 + (n - 128)];
  Bp[idx] = bf16_rne(v);
}

__global__ void bias2_kernel(const float* __restrict__ b2, float* __restrict__ bias2) {
  int j = threadIdx.x;  // 256
  bias2[j] = (j < 128) ? b2[j] : 0.0f;
}

// ---------------- bf16 MFMA GEMM: C[M_pad,256] = A[M_pad,256] @ Bp ----------------
// Block: 256 threads (4 waves), 128x128 C tile, grid (M_pad/128, 2).
// mode 0: out = bf16 relu(acc + bias[col]) into out0 [M,256]
// mode 1: out = f32 acc + bias2[col]; blockIdx.y==0 -> out0 [M,128], y==1 -> out1 [M,128]
__global__ __launch_bounds__(256) void gemm_mfma(const short* __restrict__ A,
                                                 const short* __restrict__ Bp,
                                                 const float* __restrict__ bias,
                                                 void* __restrict__ out0,
                                                 void* __restrict__ out1,
                                                 int M_pad, int mode) {
  __shared__ __align__(16) short As[4096];  // 8 frags x 1KB, frag-packed
  __shared__ __align__(16) short Bs[4096];
  int tid = threadIdx.x;
  int w = tid >> 6;      // wave 0..3
  int lane = tid & 63;
  int wr = w >> 1;       // wave row-half (0..1)
  int wc = w & 1;        // wave col-half (0..1)
  int bm = blockIdx.x * 128;
  int bn = blockIdx.y * 128;

  f32x4 acc[4][4];
  #pragma unroll
  for (int i = 0; i < 4; ++i)
    #pragma unroll
    for (int j = 0; j < 4; ++j) acc[i][j] = (f32x4)(0.0f);

  for (int kb = 0; kb < 8; ++kb) {
    // stage A: 8 frags, wave w stages frags w and 4+w
    #pragma unroll
    for (int q = 0; q < 2; ++q) {
      int f = q * 4 + w;
      int row = bm + f * 16 + (lane & 15);
      const short* g = A + (size_t)row * 256 + kb * 32 + (lane >> 4) * 8;
      async_copy16(g, &As[f * 512]);
    }
    // stage B: 8 frags (global frag idx = kb*16 + bn/16 + f)
    #pragma unroll
    for (int q = 0; q < 2; ++q) {
      int f = q * 4 + w;
      const short* g = Bp + ((size_t)(kb * 16 + (bn >> 4) + f) * 64 + lane) * 8;
      async_copy16(g, &Bs[f * 512]);
    }
    __syncthreads();

    bf16x8 af[4], bf[4];
    #pragma unroll
    for (int i = 0; i < 4; ++i)
      af[i] = *(const bf16x8*)&As[(wr * 4 + i) * 512 + lane * 8];
    #pragma unroll
    for (int j = 0; j < 4; ++j)
      bf[j] = *(const bf16x8*)&Bs[(wc * 4 + j) * 512 + lane * 8];

    #pragma unroll
    for (int i = 0; i < 4; ++i)
      #pragma unroll
      for (int j = 0; j < 4; ++j)
        acc[i][j] = __builtin_amdgcn_mfma_f32_16x16x32_bf16(af[i], bf[j], acc[i][j], 0, 0, 0);
    __syncthreads();
  }

  // epilogue: C/D layout col=lane&15, row=(lane>>4)*4+reg
  int crow0 = (lane >> 4) * 4;
  int ccol = lane & 15;
  #pragma unroll
  for (int i = 0; i < 4; ++i) {
    #pragma unroll
    for (int j = 0; j < 4; ++j) {
      int col_loc = wc * 64 + j * 16 + ccol;   // 0..127 within block
      int col = bn + col_loc;                  // 0..255 global
      #pragma unroll
      for (int r = 0; r < 4; ++r) {
        int row = bm + wr * 64 + i * 16 + crow0 + r;
        float v = acc[i][j][r] + bias[col];
        if (mode == 0) {
          v = fmaxf(v, 0.0f);
          ((short*)out0)[(size_t)row * 256 + col] = bf16_rne(v);
        } else {
          float* o = (blockIdx.y == 0) ? (float*)out0 : (float*)out1;
          o[(size_t)row * 128 + col_loc] = v;
        }
      }
    }
  }
}

// ---------------- fused: out = log_softmax(utop + inv_deg * sum_{e} t2[src]) ----------------
__global__ __launch_bounds__(128) void final_kernel(const float* __restrict__ utop,
                                                    const float* __restrict__ t2,
                                                    const int* __restrict__ offsets,
                                                    const int* __restrict__ ssrc,
                                                    const float* __restrict__ inv_deg,
                                                    float* __restrict__ out) {
  int n = blockIdx.x;
  int d = threadIdx.x;  // 128
  int s = offsets[n], e = offsets[n + 1];
  float a0 = 0.f, a1 = 0.f, a2 = 0.f, a3 = 0.f;
  int i = s;
  for (; i + 4 <= e; i += 4) {
    int s0 = ssrc[i], s1 = ssrc[i + 1], s2 = ssrc[i + 2], s3 = ssrc[i + 3];
    a0 += t2[(size_t)s0 * 128 + d];
    a1 += t2[(size_t)s1 * 128 + d];
    a2 += t2[(size_t)s2 * 128 + d];
    a3 += t2[(size_t)s3 * 128 + d];
  }
  for (; i < e; ++i) a0 += t2[(size_t)ssrc[i] * 128 + d];
  float v = utop[(size_t)n * 128 + d] + (a0 + a1 + a2 + a3) * inv_deg[n];

  __shared__ float sm[2], ss[2];
  float m = v;
  #pragma unroll
  for (int off = 1; off < 64; off <<= 1) m = fmaxf(m, __shfl_xor(m, off, 64));
  if ((d & 63) == 0) sm[d >> 6] = m;
  __syncthreads();
  m = fmaxf(sm[0], sm[1]);
  float ev = expf(v - m);
  float su = ev;
  #pragma unroll
  for (int off = 1; off < 64; off <<= 1) su += __shfl_xor(su, off, 64);
  if ((d & 63) == 0) ss[d >> 6] = su;
  __syncthreads();
  su = ss[0] + ss[1];
  out[(size_t)n * 128 + d] = v - m - logf(su);
}

extern "C" void kernel_launch(void* const* d_in, const int* in_sizes, int n_in,
                              void* d_out, int out_size, void* d_ws, size_t ws_size,
                              hipStream_t stream) {
  const float* x        = (const float*)d_in[0];
  const int*   edge_src = (const int*)d_in[1];
  const int*   edge_dst = (const int*)d_in[2];
  const float* W1       = (const float*)d_in[3];
  const float* b1       = (const float*)d_in[4];
  const float* W2       = (const float*)d_in[5];
  const float* b2       = (const float*)d_in[6];
  float* out = (float*)d_out;

  const int D_IN = 128;
  const int N = in_sizes[0] / D_IN;
  const int E = in_sizes[1];
  const int M_pad = ((N + 127) / 128) * 128;

  // ---- workspace layout ----
  char* ws = (char*)d_ws;
  size_t p = 0;
  auto take = [&](size_t bytes) -> size_t {
    size_t r = p;
    p += (bytes + 255) & ~(size_t)255;
    return r;
  };
  size_t deg_off   = take((size_t)N * 4);
  size_t cur_off   = take((size_t)N * 4);
  size_t inv_off   = take((size_t)N * 4);
  size_t offs_off  = take((size_t)(N + 1) * 4);
  size_t part_off  = take((size_t)64 * 4);
  size_t ssrc_off  = take((size_t)E * 4);
  size_t A1_off    = take((size_t)M_pad * 256 * 2);   // bf16 [x | agg1]
  size_t h_off     = take((size_t)M_pad * 256 * 2);   // bf16 h
  size_t B1p_off   = take((size_t)256 * 256 * 2);
  size_t B2p_off   = take((size_t)256 * 256 * 2);
  size_t bias2_off = take((size_t)256 * 4);
  size_t utop_off  = take((size_t)M_pad * 128 * 4);   // f32
  size_t t2_off    = take((size_t)M_pad * 128 * 4);   // f32
  (void)ws_size;

  int*   deg     = (int*)(ws + deg_off);
  int*   cursor  = (int*)(ws + cur_off);
  float* inv_deg = (float*)(ws + inv_off);
  int*   offsets = (int*)(ws + offs_off);
  int*   part    = (int*)(ws + part_off);
  int*   ssrc    = (int*)(ws + ssrc_off);
  short* A1      = (short*)(ws + A1_off);
  short* h       = (short*)(ws + h_off);
  short* B1p     = (short*)(ws + B1p_off);
  short* B2p     = (short*)(ws + B2p_off);
  float* bias2   = (float*)(ws + bias2_off);
  float* utop    = (float*)(ws + utop_off);
  float* t2      = (float*)(ws + t2_off);

  hipMemsetAsync(deg, 0, (size_t)N * 4, stream);
  hipMemsetAsync(cursor, 0, (size_t)N * 4, stream);

  int eb = (E + 255) / 256;
  int sb = (N + 1023) / 1024;  // 49

  deg_kernel<<<eb, 256, 0, stream>>>(edge_dst, E, deg);
  scan1_kernel<<<sb, 1024, 0, stream>>>(deg, offsets, part, N);
  scan2_kernel<<<1, 64, 0, stream>>>(part, offsets, N, sb);
  scan3_kernel<<<sb, 1024, 0, stream>>>(offsets, part, N);
  inv_deg_kernel<<<(N + 255) / 256, 256, 0, stream>>>(deg, inv_deg, N);
  scatter_kernel<<<eb, 256, 0, stream>>>(edge_src, edge_dst, E, offsets, cursor, ssrc);

  // weight packs (independent of graph work)
  pack_w_kernel<<<256, 256, 0, stream>>>(W1, B1p, 0);
  pack_w_kernel<<<256, 256, 0, stream>>>(W2, B2p, 1);
  bias2_kernel<<<1, 256, 0, stream>>>(b2, bias2);

  // layer 1: A1 = [bf16(x) | bf16(mean_agg(x))], h = relu(A1 @ W1 + b1) in bf16
  convert_x_kernel<<<(N * 128 + 255) / 256, 256, 0, stream>>>(x, A1, N * 128);
  agg1_kernel<<<N, 128, 0, stream>>>(x, offsets, ssrc, inv_deg, A1);
  {
    dim3 grid(M_pad / 128, 2);
    gemm_mfma<<<grid, 256, 0, stream>>>(A1, B1p, b1, h, nullptr, M_pad, 0);
  }

  // layer 2: [utop | t2] = h @ [W2_top | W2_bot] (+b2 on utop)
  {
    dim3 grid(M_pad / 128, 2);
    gemm_mfma<<<grid, 256, 0, stream>>>(h, B2p, bias2, utop, t2, M_pad, 1);
  }

  // out = log_softmax(utop + inv_deg * segment_sum(t2[src]))
  final_kernel<<<N, 128, 0, stream>>>(utop, t2, offsets, ssrc, inv_deg, out);
}

// Round 3
// 314.565 us; speedup vs baseline: 2.2870x; 1.1255x over previous
//
#include <hip/hip_runtime.h>
#include <cstdint>
#include <cstddef>

typedef __attribute__((ext_vector_type(8))) short bf16x8;
typedef __attribute__((ext_vector_type(4))) float f32x4;

__device__ inline short bf16_rne(float f) {
  unsigned u = __builtin_bit_cast(unsigned, f);
  u += 0x7fff + ((u >> 16) & 1);
  return (short)(u >> 16);
}

__device__ inline float bf16lo(unsigned v) { return __builtin_bit_cast(float, v << 16); }
__device__ inline float bf16hi(unsigned v) { return __builtin_bit_cast(float, v & 0xffff0000u); }

__device__ inline unsigned pack2(float a, float b) {
  return ((unsigned)(unsigned short)bf16_rne(a)) | (((unsigned)(unsigned short)bf16_rne(b)) << 16);
}

__device__ inline void async_copy16(const void* g, void* l) {
  __builtin_amdgcn_global_load_lds((const __attribute__((address_space(1))) void*)g,
                                   (__attribute__((address_space(3))) void*)l, 16, 0, 0);
}

// ---------------- degree histogram ----------------
__global__ void deg_kernel(const int* __restrict__ dst, int E, int* __restrict__ deg) {
  int e = blockIdx.x * blockDim.x + threadIdx.x;
  if (e < E) atomicAdd(&deg[dst[e]], 1);
}

__global__ void inv_deg_kernel(const int* __restrict__ deg, float* __restrict__ inv, int N) {
  int i = blockIdx.x * blockDim.x + threadIdx.x;
  if (i < N) inv[i] = 1.0f / fmaxf((float)deg[i], 1.0f);
}

// ---------------- hierarchical scan ----------------
__global__ __launch_bounds__(1024) void scan1_kernel(const int* __restrict__ deg,
                                                     int* __restrict__ offsets,
                                                     int* __restrict__ part, int n) {
  __shared__ int buf[1024];
  int tid = threadIdx.x;
  int i = blockIdx.x * 1024 + tid;
  int v = (i < n) ? deg[i] : 0;
  buf[tid] = v;
  __syncthreads();
  #pragma unroll
  for (int off = 1; off < 1024; off <<= 1) {
    int t = (tid >= off) ? buf[tid - off] : 0;
    __syncthreads();
    buf[tid] += t;
    __syncthreads();
  }
  if (i < n) offsets[i] = buf[tid] - v;
  if (tid == 1023) part[blockIdx.x] = buf[1023];
}

__global__ __launch_bounds__(64) void scan2_kernel(int* __restrict__ part,
                                                   int* __restrict__ offsets, int n, int B) {
  int lane = threadIdx.x;
  int v = (lane < B) ? part[lane] : 0;
  int orig = v;
  #pragma unroll
  for (int off = 1; off < 64; off <<= 1) {
    int t = __shfl_up(v, off, 64);
    if (lane >= off) v += t;
  }
  if (lane < B) part[lane] = v - orig;
  if (lane == 63) offsets[n] = v;
}

__global__ __launch_bounds__(1024) void scan3_kernel(int* __restrict__ offsets,
                                                     const int* __restrict__ part, int n) {
  int i = blockIdx.x * 1024 + threadIdx.x;
  if (i < n) offsets[i] += part[blockIdx.x];
}

// ---------------- scatter edges into CSR order ----------------
__global__ void scatter_kernel(const int* __restrict__ src, const int* __restrict__ dst, int E,
                               const int* __restrict__ offsets, int* __restrict__ cursor,
                               int* __restrict__ ssrc) {
  int e = blockIdx.x * blockDim.x + threadIdx.x;
  if (e < E) {
    int d = dst[e];
    int pos = offsets[d] + atomicAdd(&cursor[d], 1);
    ssrc[pos] = src[e];
  }
}

// ---------------- convert x -> bf16 into A1 left half ----------------
__global__ void convert_x_kernel(const float* __restrict__ x, unsigned short* __restrict__ A1,
                                 int total) {
  int idx = blockIdx.x * blockDim.x + threadIdx.x;  // pairs
  if (idx < total / 2) {
    int n = idx >> 6, dp = idx & 63;  // 64 pairs per row
    float2 v = ((const float2*)x)[idx];
    *(unsigned*)(A1 + (size_t)n * 256 + dp * 2) = pack2(v.x, v.y);
  }
}

// ---------------- layer-1 aggregation: wave per node, bf16 gather ----------------
// reads left half of A1 rows (stride 256 ushorts), writes right half.
__global__ __launch_bounds__(256) void agg1_kernel(const unsigned short* __restrict__ A1,
                                                   const int* __restrict__ offsets,
                                                   const int* __restrict__ ssrc,
                                                   const float* __restrict__ inv_deg,
                                                   unsigned short* __restrict__ A1out, int N) {
  int node = blockIdx.x * 4 + (threadIdx.x >> 6);
  if (node >= N) return;
  int lane = threadIdx.x & 63;
  int s = offsets[node], e = offsets[node + 1];
  float a0 = 0.f, a1 = 0.f, b0 = 0.f, b1 = 0.f, c0 = 0.f, c1 = 0.f, d0 = 0.f, d1 = 0.f;
  int i = s;
  for (; i + 4 <= e; i += 4) {
    int s0 = ssrc[i], s1 = ssrc[i + 1], s2 = ssrc[i + 2], s3 = ssrc[i + 3];
    unsigned v0 = *(const unsigned*)(A1 + (size_t)s0 * 256 + lane * 2);
    unsigned v1 = *(const unsigned*)(A1 + (size_t)s1 * 256 + lane * 2);
    unsigned v2 = *(const unsigned*)(A1 + (size_t)s2 * 256 + lane * 2);
    unsigned v3 = *(const unsigned*)(A1 + (size_t)s3 * 256 + lane * 2);
    a0 += bf16lo(v0); a1 += bf16hi(v0);
    b0 += bf16lo(v1); b1 += bf16hi(v1);
    c0 += bf16lo(v2); c1 += bf16hi(v2);
    d0 += bf16lo(v3); d1 += bf16hi(v3);
  }
  for (; i < e; ++i) {
    unsigned v = *(const unsigned*)(A1 + (size_t)ssrc[i] * 256 + lane * 2);
    a0 += bf16lo(v); a1 += bf16hi(v);
  }
  float id = inv_deg[node];
  float r0 = (a0 + b0 + c0 + d0) * id;
  float r1 = (a1 + b1 + c1 + d1) * id;
  *(unsigned*)(A1out + (size_t)node * 256 + 128 + lane * 2) = pack2(r0, r1);
}

// ---------------- weight pack into frag-ordered bf16 layout ----------------
__global__ void pack_w_kernel(const float* __restrict__ W, short* __restrict__ Bp, int mode) {
  int idx = blockIdx.x * 256 + threadIdx.x;  // 65536 total
  int j = idx & 7;
  int L = (idx >> 3) & 63;
  int nt = (idx >> 9) & 15;
  int kb = idx >> 13;
  int k = kb * 32 + (L >> 4) * 8 + j;
  int n = nt * 16 + (L & 15);
  float v;
  if (mode == 0) v = W[(size_t)k * 256 + n];
  else v = (n < 128) ? W[(size_t)k * 128 + n] : W[(size_t)(256 + k) * 128 + (n - 128)];
  Bp[idx] = bf16_rne(v);
}

__global__ void bias2_kernel(const float* __restrict__ b2, float* __restrict__ bias2) {
  int j = threadIdx.x;  // 256
  bias2[j] = (j < 128) ? b2[j] : 0.0f;
}

// ---------------- bf16 MFMA GEMM: C[M_pad,256] = A[M_pad,256] @ Bp ----------------
// mode 0: out0 = bf16 relu(acc+bias) [M,256]
// mode 1: y==0 -> out0 f32 [M,128] (utop); y==1 -> out1 bf16 [M,128] (t2)
__global__ __launch_bounds__(256) void gemm_mfma(const short* __restrict__ A,
                                                 const short* __restrict__ Bp,
                                                 const float* __restrict__ bias,
                                                 void* __restrict__ out0,
                                                 void* __restrict__ out1,
                                                 int M_pad, int mode) {
  __shared__ __align__(16) short As[4096];
  __shared__ __align__(16) short Bs[4096];
  int tid = threadIdx.x;
  int w = tid >> 6;
  int lane = tid & 63;
  int wr = w >> 1;
  int wc = w & 1;
  int bm = blockIdx.x * 128;
  int bn = blockIdx.y * 128;

  f32x4 acc[4][4];
  #pragma unroll
  for (int i = 0; i < 4; ++i)
    #pragma unroll
    for (int j = 0; j < 4; ++j) acc[i][j] = (f32x4)(0.0f);

  for (int kb = 0; kb < 8; ++kb) {
    #pragma unroll
    for (int q = 0; q < 2; ++q) {
      int f = q * 4 + w;
      int row = bm + f * 16 + (lane & 15);
      const short* g = A + (size_t)row * 256 + kb * 32 + (lane >> 4) * 8;
      async_copy16(g, &As[f * 512]);
    }
    #pragma unroll
    for (int q = 0; q < 2; ++q) {
      int f = q * 4 + w;
      const short* g = Bp + ((size_t)(kb * 16 + (bn >> 4) + f) * 64 + lane) * 8;
      async_copy16(g, &Bs[f * 512]);
    }
    __syncthreads();

    bf16x8 af[4], bfr[4];
    #pragma unroll
    for (int i = 0; i < 4; ++i)
      af[i] = *(const bf16x8*)&As[(wr * 4 + i) * 512 + lane * 8];
    #pragma unroll
    for (int j = 0; j < 4; ++j)
      bfr[j] = *(const bf16x8*)&Bs[(wc * 4 + j) * 512 + lane * 8];

    #pragma unroll
    for (int i = 0; i < 4; ++i)
      #pragma unroll
      for (int j = 0; j < 4; ++j)
        acc[i][j] = __builtin_amdgcn_mfma_f32_16x16x32_bf16(af[i], bfr[j], acc[i][j], 0, 0, 0);
    __syncthreads();
  }

  int crow0 = (lane >> 4) * 4;
  int ccol = lane & 15;
  #pragma unroll
  for (int i = 0; i < 4; ++i) {
    #pragma unroll
    for (int j = 0; j < 4; ++j) {
      int col_loc = wc * 64 + j * 16 + ccol;
      int col = bn + col_loc;
      #pragma unroll
      for (int r = 0; r < 4; ++r) {
        int row = bm + wr * 64 + i * 16 + crow0 + r;
        float v = acc[i][j][r] + bias[col];
        if (mode == 0) {
          v = fmaxf(v, 0.0f);
          ((short*)out0)[(size_t)row * 256 + col] = bf16_rne(v);
        } else if (blockIdx.y == 0) {
          ((float*)out0)[(size_t)row * 128 + col_loc] = v;
        } else {
          ((short*)out1)[(size_t)row * 128 + col_loc] = bf16_rne(v);
        }
      }
    }
  }
}

// ---------------- fused: out = log_softmax(utop + inv_deg * sum t2b[src]) ----------------
// wave per node; 2 dims per lane; bf16 gather; shuffle-only softmax.
__global__ __launch_bounds__(256) void final_kernel(const float* __restrict__ utop,
                                                    const unsigned short* __restrict__ t2b,
                                                    const int* __restrict__ offsets,
                                                    const int* __restrict__ ssrc,
                                                    const float* __restrict__ inv_deg,
                                                    float* __restrict__ out, int N) {
  int node = blockIdx.x * 4 + (threadIdx.x >> 6);
  if (node >= N) return;
  int lane = threadIdx.x & 63;
  int s = offsets[node], e = offsets[node + 1];
  float a0 = 0.f, a1 = 0.f, b0 = 0.f, b1 = 0.f, c0 = 0.f, c1 = 0.f, d0 = 0.f, d1 = 0.f;
  int i = s;
  for (; i + 4 <= e; i += 4) {
    int s0 = ssrc[i], s1 = ssrc[i + 1], s2 = ssrc[i + 2], s3 = ssrc[i + 3];
    unsigned v0 = *(const unsigned*)(t2b + (size_t)s0 * 128 + lane * 2);
    unsigned v1 = *(const unsigned*)(t2b + (size_t)s1 * 128 + lane * 2);
    unsigned v2 = *(const unsigned*)(t2b + (size_t)s2 * 128 + lane * 2);
    unsigned v3 = *(const unsigned*)(t2b + (size_t)s3 * 128 + lane * 2);
    a0 += bf16lo(v0); a1 += bf16hi(v0);
    b0 += bf16lo(v1); b1 += bf16hi(v1);
    c0 += bf16lo(v2); c1 += bf16hi(v2);
    d0 += bf16lo(v3); d1 += bf16hi(v3);
  }
  for (; i < e; ++i) {
    unsigned v = *(const unsigned*)(t2b + (size_t)ssrc[i] * 128 + lane * 2);
    a0 += bf16lo(v); a1 += bf16hi(v);
  }
  float id = inv_deg[node];
  float2 u = *(const float2*)(utop + (size_t)node * 128 + lane * 2);
  float v0 = u.x + (a0 + b0 + c0 + d0) * id;
  float v1 = u.y + (a1 + b1 + c1 + d1) * id;

  float m = fmaxf(v0, v1);
  #pragma unroll
  for (int off = 1; off < 64; off <<= 1) m = fmaxf(m, __shfl_xor(m, off, 64));
  float su = expf(v0 - m) + expf(v1 - m);
  #pragma unroll
  for (int off = 1; off < 64; off <<= 1) su += __shfl_xor(su, off, 64);
  float ls = m + logf(su);
  float2 o;
  o.x = v0 - ls;
  o.y = v1 - ls;
  *(float2*)(out + (size_t)node * 128 + lane * 2) = o;
}

extern "C" void kernel_launch(void* const* d_in, const int* in_sizes, int n_in,
                              void* d_out, int out_size, void* d_ws, size_t ws_size,
                              hipStream_t stream) {
  const float* x        = (const float*)d_in[0];
  const int*   edge_src = (const int*)d_in[1];
  const int*   edge_dst = (const int*)d_in[2];
  const float* W1       = (const float*)d_in[3];
  const float* b1       = (const float*)d_in[4];
  const float* W2       = (const float*)d_in[5];
  const float* b2       = (const float*)d_in[6];
  float* out = (float*)d_out;

  const int D_IN = 128;
  const int N = in_sizes[0] / D_IN;
  const int E = in_sizes[1];
  const int M_pad = ((N + 127) / 128) * 128;

  char* ws = (char*)d_ws;
  size_t p = 0;
  auto take = [&](size_t bytes) -> size_t {
    size_t r = p;
    p += (bytes + 255) & ~(size_t)255;
    return r;
  };
  size_t deg_off   = take((size_t)N * 4);
  size_t cur_off   = take((size_t)N * 4);
  size_t inv_off   = take((size_t)N * 4);
  size_t offs_off  = take((size_t)(N + 1) * 4);
  size_t part_off  = take((size_t)64 * 4);
  size_t ssrc_off  = take((size_t)E * 4);
  size_t A1_off    = take((size_t)M_pad * 256 * 2);   // bf16 [x | agg1]
  size_t h_off     = take((size_t)M_pad * 256 * 2);   // bf16 h
  size_t B1p_off   = take((size_t)256 * 256 * 2);
  size_t B2p_off   = take((size_t)256 * 256 * 2);
  size_t bias2_off = take((size_t)256 * 4);
  size_t utop_off  = take((size_t)M_pad * 128 * 4);   // f32
  size_t t2_off    = take((size_t)M_pad * 128 * 2);   // bf16
  (void)ws_size;

  int*   deg     = (int*)(ws + deg_off);
  int*   cursor  = (int*)(ws + cur_off);
  float* inv_deg = (float*)(ws + inv_off);
  int*   offsets = (int*)(ws + offs_off);
  int*   part    = (int*)(ws + part_off);
  int*   ssrc    = (int*)(ws + ssrc_off);
  unsigned short* A1 = (unsigned short*)(ws + A1_off);
  short* h       = (short*)(ws + h_off);
  short* B1p     = (short*)(ws + B1p_off);
  short* B2p     = (short*)(ws + B2p_off);
  float* bias2   = (float*)(ws + bias2_off);
  float* utop    = (float*)(ws + utop_off);
  unsigned short* t2b = (unsigned short*)(ws + t2_off);

  hipMemsetAsync(deg, 0, (size_t)N * 4, stream);
  hipMemsetAsync(cursor, 0, (size_t)N * 4, stream);

  int eb = (E + 255) / 256;
  int sb = (N + 1023) / 1024;

  deg_kernel<<<eb, 256, 0, stream>>>(edge_dst, E, deg);
  scan1_kernel<<<sb, 1024, 0, stream>>>(deg, offsets, part, N);
  scan2_kernel<<<1, 64, 0, stream>>>(part, offsets, N, sb);
  scan3_kernel<<<sb, 1024, 0, stream>>>(offsets, part, N);
  inv_deg_kernel<<<(N + 255) / 256, 256, 0, stream>>>(deg, inv_deg, N);
  scatter_kernel<<<eb, 256, 0, stream>>>(edge_src, edge_dst, E, offsets, cursor, ssrc);

  pack_w_kernel<<<256, 256, 0, stream>>>(W1, B1p, 0);
  pack_w_kernel<<<256, 256, 0, stream>>>(W2, B2p, 1);
  bias2_kernel<<<1, 256, 0, stream>>>(b2, bias2);

  convert_x_kernel<<<(N * 64 + 255) / 256, 256, 0, stream>>>(x, A1, N * 128);
  agg1_kernel<<<(N + 3) / 4, 256, 0, stream>>>(A1, offsets, ssrc, inv_deg, A1, N);
  {
    dim3 grid(M_pad / 128, 2);
    gemm_mfma<<<grid, 256, 0, stream>>>((const short*)A1, B1p, b1, h, nullptr, M_pad, 0);
  }
  {
    dim3 grid(M_pad / 128, 2);
    gemm_mfma<<<grid, 256, 0, stream>>>(h, B2p, bias2, utop, t2b, M_pad, 1);
  }
  final_kernel<<<(N + 3) / 4, 256, 0, stream>>>(utop, t2b, offsets, ssrc, inv_deg, out, N);
}

// Round 4
// 280.054 us; speedup vs baseline: 2.5688x; 1.1232x over previous
//
#include <hip/hip_runtime.h>
#include <cstdint>
#include <cstddef>

typedef __attribute__((ext_vector_type(8))) short bf16x8;
typedef __attribute__((ext_vector_type(4))) float f32x4;

__device__ inline short bf16_rne(float f) {
  unsigned u = __builtin_bit_cast(unsigned, f);
  u += 0x7fff + ((u >> 16) & 1);
  return (short)(u >> 16);
}

__device__ inline float bf16lo(unsigned v) { return __builtin_bit_cast(float, v << 16); }
__device__ inline float bf16hi(unsigned v) { return __builtin_bit_cast(float, v & 0xffff0000u); }

__device__ inline unsigned pack2(float a, float b) {
  return ((unsigned)(unsigned short)bf16_rne(a)) | (((unsigned)(unsigned short)bf16_rne(b)) << 16);
}

__device__ inline void async_copy16(const void* g, void* l) {
  __builtin_amdgcn_global_load_lds((const __attribute__((address_space(1))) void*)g,
                                   (__attribute__((address_space(3))) void*)l, 16, 0, 0);
}

// ================= CSR build: bucketed counting sort =================
// Buckets of 256 nodes (bucket = dst >> 8). NB buckets, SB=64 edge-chunk blocks.

// phase 1a: per-chunk histogram over buckets -> histT[bucket*SB + blk]
__global__ __launch_bounds__(256) void bucket_hist(const int* __restrict__ dst, int E, int EPB,
                                                   int* __restrict__ histT, int SB, int NB) {
  __shared__ int h[256];
  int tid = threadIdx.x;
  h[tid] = 0;
  __syncthreads();
  int start = blockIdx.x * EPB, end = min(E, start + EPB);
  for (int i = start + tid; i < end; i += 256) atomicAdd(&h[((unsigned)dst[i]) >> 8], 1);
  __syncthreads();
  if (tid < NB) histT[tid * SB + blockIdx.x] = h[tid];
}

// hierarchical scan (reused for histT -> excl)
__global__ __launch_bounds__(1024) void scan1_kernel(const int* __restrict__ in,
                                                     int* __restrict__ outx,
                                                     int* __restrict__ part, int n) {
  __shared__ int buf[1024];
  int tid = threadIdx.x;
  int i = blockIdx.x * 1024 + tid;
  int v = (i < n) ? in[i] : 0;
  buf[tid] = v;
  __syncthreads();
  #pragma unroll
  for (int off = 1; off < 1024; off <<= 1) {
    int t = (tid >= off) ? buf[tid - off] : 0;
    __syncthreads();
    buf[tid] += t;
    __syncthreads();
  }
  if (i < n) outx[i] = buf[tid] - v;
  if (tid == 1023) part[blockIdx.x] = buf[1023];
}

__global__ __launch_bounds__(64) void scan2_kernel(int* __restrict__ part,
                                                   int* __restrict__ outx, int n, int B) {
  int lane = threadIdx.x;
  int v = (lane < B) ? part[lane] : 0;
  int orig = v;
  #pragma unroll
  for (int off = 1; off < 64; off <<= 1) {
    int t = __shfl_up(v, off, 64);
    if (lane >= off) v += t;
  }
  if (lane < B) part[lane] = v - orig;
  if (lane == 63) outx[n] = v;
}

__global__ __launch_bounds__(1024) void scan3_kernel(int* __restrict__ outx,
                                                     const int* __restrict__ part, int n) {
  int i = blockIdx.x * 1024 + threadIdx.x;
  if (i < n) outx[i] += part[blockIdx.x];
}

// phase 1b: scatter (dst,src) pairs into bucket-grouped order (contiguous runs)
__global__ __launch_bounds__(256) void bucket_scatter(const int* __restrict__ src,
                                                      const int* __restrict__ dst, int E, int EPB,
                                                      const int* __restrict__ excl, int SB, int NB,
                                                      uint2* __restrict__ bedge) {
  __shared__ int cur[256];
  int tid = threadIdx.x;
  if (tid < NB) cur[tid] = excl[tid * SB + blockIdx.x];
  __syncthreads();
  int start = blockIdx.x * EPB, end = min(E, start + EPB);
  for (int i = start + tid; i < end; i += 256) {
    int d = dst[i];
    int p = atomicAdd(&cur[((unsigned)d) >> 8], 1);
    bedge[p] = make_uint2((unsigned)d, (unsigned)src[i]);
  }
}

// phase 2: per-bucket CSR finalize: offsets, inv_deg, ssrc (LDS hist+scan+cursors)
__global__ __launch_bounds__(256) void build_csr(const uint2* __restrict__ bedge,
                                                 const int* __restrict__ excl, int SB, int NB,
                                                 int N, int E,
                                                 int* __restrict__ offsets,
                                                 float* __restrict__ inv_deg,
                                                 int* __restrict__ ssrc) {
  __shared__ int buf[256];
  int b = blockIdx.x, tid = threadIdx.x;
  int estart = excl[b * SB];
  int eend = excl[(b + 1) * SB];  // b = NB-1 reads excl[NB*SB] = E
  buf[tid] = 0;
  __syncthreads();
  for (int i = estart + tid; i < eend; i += 256) atomicAdd(&buf[bedge[i].x & 255u], 1);
  __syncthreads();
  int cnt = buf[tid];
  #pragma unroll
  for (int off = 1; off < 256; off <<= 1) {
    int t = (tid >= off) ? buf[tid - off] : 0;
    __syncthreads();
    buf[tid] += t;
    __syncthreads();
  }
  int excl_l = buf[tid] - cnt;
  int node = (b << 8) + tid;
  if (node < N) {
    offsets[node] = estart + excl_l;
    inv_deg[node] = 1.0f / fmaxf((float)cnt, 1.0f);
  }
  if (node == N) offsets[N] = E;
  __syncthreads();
  buf[tid] = estart + excl_l;  // cursor
  __syncthreads();
  for (int i = estart + tid; i < eend; i += 256) {
    uint2 e2 = bedge[i];
    int p = atomicAdd(&buf[e2.x & 255u], 1);
    ssrc[p] = (int)e2.y;
  }
}

// ================= feature pipeline =================

__global__ void convert_x_kernel(const float* __restrict__ x, unsigned* __restrict__ A1u,
                                 int npairs) {
  int idx = blockIdx.x * blockDim.x + threadIdx.x;  // pairs
  if (idx < npairs) {
    int n = idx >> 6, dp = idx & 63;  // 64 uint-pairs per row's left half
    float2 v = ((const float2*)x)[idx];
    A1u[(size_t)n * 128 + dp] = pack2(v.x, v.y);
  }
}

// layer-1 aggregation: wave per node, pair-mode bf16 gather from A1 left halves.
// A1 row = 64 uint2 (256 ushorts); left half = uint2 0..31; right half 32..63.
__global__ __launch_bounds__(256) void agg1_kernel(const uint2* __restrict__ A2,
                                                   const int* __restrict__ offsets,
                                                   const int* __restrict__ ssrc,
                                                   const float* __restrict__ inv_deg,
                                                   uint2* __restrict__ A2out, int N) {
  int node = blockIdx.x * 4 + (threadIdx.x >> 6);
  if (node >= N) return;
  int lane = threadIdx.x & 63;
  int half = lane >> 5;
  int l = lane & 31;
  int s = offsets[node], e = offsets[node + 1];
  float a0 = 0.f, a1 = 0.f, a2 = 0.f, a3 = 0.f;
  int i = s;
  for (; i + 8 <= e; i += 8) {
    int sA = ssrc[i + half], sB = ssrc[i + 2 + half];
    int sC = ssrc[i + 4 + half], sD = ssrc[i + 6 + half];
    uint2 u = A2[((unsigned)sA << 6) + l];
    uint2 v = A2[((unsigned)sB << 6) + l];
    uint2 w = A2[((unsigned)sC << 6) + l];
    uint2 z = A2[((unsigned)sD << 6) + l];
    a0 += bf16lo(u.x); a1 += bf16hi(u.x); a2 += bf16lo(u.y); a3 += bf16hi(u.y);
    a0 += bf16lo(v.x); a1 += bf16hi(v.x); a2 += bf16lo(v.y); a3 += bf16hi(v.y);
    a0 += bf16lo(w.x); a1 += bf16hi(w.x); a2 += bf16lo(w.y); a3 += bf16hi(w.y);
    a0 += bf16lo(z.x); a1 += bf16hi(z.x); a2 += bf16lo(z.y); a3 += bf16hi(z.y);
  }
  for (; i + 2 <= e; i += 2) {
    int sA = ssrc[i + half];
    uint2 u = A2[((unsigned)sA << 6) + l];
    a0 += bf16lo(u.x); a1 += bf16hi(u.x); a2 += bf16lo(u.y); a3 += bf16hi(u.y);
  }
  if (i < e && half == 0) {
    uint2 u = A2[((unsigned)ssrc[i] << 6) + l];
    a0 += bf16lo(u.x); a1 += bf16hi(u.x); a2 += bf16lo(u.y); a3 += bf16hi(u.y);
  }
  a0 += __shfl_xor(a0, 32, 64);
  a1 += __shfl_xor(a1, 32, 64);
  a2 += __shfl_xor(a2, 32, 64);
  a3 += __shfl_xor(a3, 32, 64);
  if (half == 0) {
    float id = inv_deg[node];
    A2out[((unsigned)node << 6) + 32 + l] =
        make_uint2(pack2(a0 * id, a1 * id), pack2(a2 * id, a3 * id));
  }
}

// ================= weight pack + GEMM (unchanged structure) =================
__global__ void pack_w_kernel(const float* __restrict__ W, short* __restrict__ Bp, int mode) {
  int idx = blockIdx.x * 256 + threadIdx.x;  // 65536
  int j = idx & 7;
  int L = (idx >> 3) & 63;
  int nt = (idx >> 9) & 15;
  int kb = idx >> 13;
  int k = kb * 32 + (L >> 4) * 8 + j;
  int n = nt * 16 + (L & 15);
  float v;
  if (mode == 0) v = W[(size_t)k * 256 + n];
  else v = (n < 128) ? W[(size_t)k * 128 + n] : W[(size_t)(256 + k) * 128 + (n - 128)];
  Bp[idx] = bf16_rne(v);
}

__global__ void bias2_kernel(const float* __restrict__ b2, float* __restrict__ bias2) {
  int j = threadIdx.x;
  bias2[j] = (j < 128) ? b2[j] : 0.0f;
}

__global__ __launch_bounds__(256) void gemm_mfma(const short* __restrict__ A,
                                                 const short* __restrict__ Bp,
                                                 const float* __restrict__ bias,
                                                 void* __restrict__ out0,
                                                 void* __restrict__ out1,
                                                 int M_pad, int mode) {
  __shared__ __align__(16) short As[4096];
  __shared__ __align__(16) short Bs[4096];
  int tid = threadIdx.x;
  int w = tid >> 6;
  int lane = tid & 63;
  int wr = w >> 1;
  int wc = w & 1;
  int bm = blockIdx.x * 128;
  int bn = blockIdx.y * 128;

  f32x4 acc[4][4];
  #pragma unroll
  for (int i = 0; i < 4; ++i)
    #pragma unroll
    for (int j = 0; j < 4; ++j) acc[i][j] = (f32x4)(0.0f);

  for (int kb = 0; kb < 8; ++kb) {
    #pragma unroll
    for (int q = 0; q < 2; ++q) {
      int f = q * 4 + w;
      int row = bm + f * 16 + (lane & 15);
      const short* g = A + (size_t)row * 256 + kb * 32 + (lane >> 4) * 8;
      async_copy16(g, &As[f * 512]);
    }
    #pragma unroll
    for (int q = 0; q < 2; ++q) {
      int f = q * 4 + w;
      const short* g = Bp + ((size_t)(kb * 16 + (bn >> 4) + f) * 64 + lane) * 8;
      async_copy16(g, &Bs[f * 512]);
    }
    __syncthreads();

    bf16x8 af[4], bfr[4];
    #pragma unroll
    for (int i = 0; i < 4; ++i)
      af[i] = *(const bf16x8*)&As[(wr * 4 + i) * 512 + lane * 8];
    #pragma unroll
    for (int j = 0; j < 4; ++j)
      bfr[j] = *(const bf16x8*)&Bs[(wc * 4 + j) * 512 + lane * 8];

    #pragma unroll
    for (int i = 0; i < 4; ++i)
      #pragma unroll
      for (int j = 0; j < 4; ++j)
        acc[i][j] = __builtin_amdgcn_mfma_f32_16x16x32_bf16(af[i], bfr[j], acc[i][j], 0, 0, 0);
    __syncthreads();
  }

  int crow0 = (lane >> 4) * 4;
  int ccol = lane & 15;
  #pragma unroll
  for (int i = 0; i < 4; ++i) {
    #pragma unroll
    for (int j = 0; j < 4; ++j) {
      int col_loc = wc * 64 + j * 16 + ccol;
      int col = bn + col_loc;
      #pragma unroll
      for (int r = 0; r < 4; ++r) {
        int row = bm + wr * 64 + i * 16 + crow0 + r;
        float v = acc[i][j][r] + bias[col];
        if (mode == 0) {
          v = fmaxf(v, 0.0f);
          ((short*)out0)[(size_t)row * 256 + col] = bf16_rne(v);
        } else if (blockIdx.y == 0) {
          ((float*)out0)[(size_t)row * 128 + col_loc] = v;
        } else {
          ((short*)out1)[(size_t)row * 128 + col_loc] = bf16_rne(v);
        }
      }
    }
  }
}

// ================= fused final: aggregate t2 + utop + log_softmax =================
// t2b row = 32 uint2; utop/out row = 32 float4. Pair-mode gather, half-wave epilogue.
__global__ __launch_bounds__(256) void final_kernel(const float4* __restrict__ utop4,
                                                    const uint2* __restrict__ T2,
                                                    const int* __restrict__ offsets,
                                                    const int* __restrict__ ssrc,
                                                    const float* __restrict__ inv_deg,
                                                    float4* __restrict__ out4, int N) {
  int node = blockIdx.x * 4 + (threadIdx.x >> 6);
  if (node >= N) return;
  int lane = threadIdx.x & 63;
  int half = lane >> 5;
  int l = lane & 31;
  int s = offsets[node], e = offsets[node + 1];
  float a0 = 0.f, a1 = 0.f, a2 = 0.f, a3 = 0.f;
  int i = s;
  for (; i + 8 <= e; i += 8) {
    int sA = ssrc[i + half], sB = ssrc[i + 2 + half];
    int sC = ssrc[i + 4 + half], sD = ssrc[i + 6 + half];
    uint2 u = T2[((unsigned)sA << 5) + l];
    uint2 v = T2[((unsigned)sB << 5) + l];
    uint2 w = T2[((unsigned)sC << 5) + l];
    uint2 z = T2[((unsigned)sD << 5) + l];
    a0 += bf16lo(u.x); a1 += bf16hi(u.x); a2 += bf16lo(u.y); a3 += bf16hi(u.y);
    a0 += bf16lo(v.x); a1 += bf16hi(v.x); a2 += bf16lo(v.y); a3 += bf16hi(v.y);
    a0 += bf16lo(w.x); a1 += bf16hi(w.x); a2 += bf16lo(w.y); a3 += bf16hi(w.y);
    a0 += bf16lo(z.x); a1 += bf16hi(z.x); a2 += bf16lo(z.y); a3 += bf16hi(z.y);
  }
  for (; i + 2 <= e; i += 2) {
    int sA = ssrc[i + half];
    uint2 u = T2[((unsigned)sA << 5) + l];
    a0 += bf16lo(u.x); a1 += bf16hi(u.x); a2 += bf16lo(u.y); a3 += bf16hi(u.y);
  }
  if (i < e && half == 0) {
    uint2 u = T2[((unsigned)ssrc[i] << 5) + l];
    a0 += bf16lo(u.x); a1 += bf16hi(u.x); a2 += bf16lo(u.y); a3 += bf16hi(u.y);
  }
  a0 += __shfl_xor(a0, 32, 64);
  a1 += __shfl_xor(a1, 32, 64);
  a2 += __shfl_xor(a2, 32, 64);
  a3 += __shfl_xor(a3, 32, 64);
  if (half == 0) {
    float id = inv_deg[node];
    float4 u = utop4[((unsigned)node << 5) + l];
    float v0 = u.x + a0 * id;
    float v1 = u.y + a1 * id;
    float v2 = u.z + a2 * id;
    float v3 = u.w + a3 * id;
    float m = fmaxf(fmaxf(v0, v1), fmaxf(v2, v3));
    #pragma unroll
    for (int off = 1; off < 32; off <<= 1) m = fmaxf(m, __shfl_xor(m, off, 32));
    float su = expf(v0 - m) + expf(v1 - m) + expf(v2 - m) + expf(v3 - m);
    #pragma unroll
    for (int off = 1; off < 32; off <<= 1) su += __shfl_xor(su, off, 32);
    float ls = m + logf(su);
    out4[((unsigned)node << 5) + l] = make_float4(v0 - ls, v1 - ls, v2 - ls, v3 - ls);
  }
}

extern "C" void kernel_launch(void* const* d_in, const int* in_sizes, int n_in,
                              void* d_out, int out_size, void* d_ws, size_t ws_size,
                              hipStream_t stream) {
  const float* x        = (const float*)d_in[0];
  const int*   edge_src = (const int*)d_in[1];
  const int*   edge_dst = (const int*)d_in[2];
  const float* W1       = (const float*)d_in[3];
  const float* b1       = (const float*)d_in[4];
  const float* W2       = (const float*)d_in[5];
  const float* b2       = (const float*)d_in[6];
  float* out = (float*)d_out;

  const int D_IN = 128;
  const int N = in_sizes[0] / D_IN;
  const int E = in_sizes[1];
  const int M_pad = ((N + 127) / 128) * 128;

  const int SB = 64;                     // edge-chunk blocks
  const int EPB = (E + SB - 1) / SB;     // edges per chunk
  const int NB = (N + 255) >> 8;         // node buckets (256 nodes each)
  const int M = NB * SB;                 // hist matrix size
  const int sbl = (M + 1023) / 1024;     // scan blocks (<= 64)

  char* ws = (char*)d_ws;
  size_t p = 0;
  auto take = [&](size_t bytes) -> size_t {
    size_t r = p;
    p += (bytes + 255) & ~(size_t)255;
    return r;
  };
  size_t histT_off = take((size_t)M * 4);
  size_t excl_off  = take((size_t)(M + 1) * 4);
  size_t part_off  = take((size_t)64 * 4);
  size_t bedge_off = take((size_t)E * 8);
  size_t offs_off  = take((size_t)(N + 1) * 4);
  size_t inv_off   = take((size_t)N * 4);
  size_t ssrc_off  = take((size_t)E * 4);
  size_t A1_off    = take((size_t)M_pad * 256 * 2);   // bf16 [x | agg1]
  size_t h_off     = take((size_t)M_pad * 256 * 2);   // bf16 h
  size_t B1p_off   = take((size_t)256 * 256 * 2);
  size_t B2p_off   = take((size_t)256 * 256 * 2);
  size_t bias2_off = take((size_t)256 * 4);
  size_t utop_off  = take((size_t)M_pad * 128 * 4);   // f32
  size_t t2_off    = take((size_t)M_pad * 128 * 2);   // bf16
  (void)ws_size;

  int*   histT   = (int*)(ws + histT_off);
  int*   excl    = (int*)(ws + excl_off);
  int*   part    = (int*)(ws + part_off);
  uint2* bedge   = (uint2*)(ws + bedge_off);
  int*   offsets = (int*)(ws + offs_off);
  float* inv_deg = (float*)(ws + inv_off);
  int*   ssrc    = (int*)(ws + ssrc_off);
  unsigned* A1u  = (unsigned*)(ws + A1_off);
  short* h       = (short*)(ws + h_off);
  short* B1p     = (short*)(ws + B1p_off);
  short* B2p     = (short*)(ws + B2p_off);
  float* bias2   = (float*)(ws + bias2_off);
  float* utop    = (float*)(ws + utop_off);
  unsigned short* t2b = (unsigned short*)(ws + t2_off);

  // ---- CSR build ----
  bucket_hist<<<SB, 256, 0, stream>>>(edge_dst, E, EPB, histT, SB, NB);
  scan1_kernel<<<sbl, 1024, 0, stream>>>(histT, excl, part, M);
  scan2_kernel<<<1, 64, 0, stream>>>(part, excl, M, sbl);
  scan3_kernel<<<sbl, 1024, 0, stream>>>(excl, part, M);
  bucket_scatter<<<SB, 256, 0, stream>>>(edge_src, edge_dst, E, EPB, excl, SB, NB, bedge);
  build_csr<<<NB, 256, 0, stream>>>(bedge, excl, SB, NB, N, E, offsets, inv_deg, ssrc);

  // ---- weights / conversions ----
  pack_w_kernel<<<256, 256, 0, stream>>>(W1, B1p, 0);
  pack_w_kernel<<<256, 256, 0, stream>>>(W2, B2p, 1);
  bias2_kernel<<<1, 256, 0, stream>>>(b2, bias2);
  convert_x_kernel<<<(N * 64 + 255) / 256, 256, 0, stream>>>(x, A1u, N * 64);

  // ---- layer 1 ----
  agg1_kernel<<<(N + 3) / 4, 256, 0, stream>>>((const uint2*)A1u, offsets, ssrc, inv_deg,
                                               (uint2*)A1u, N);
  {
    dim3 grid(M_pad / 128, 2);
    gemm_mfma<<<grid, 256, 0, stream>>>((const short*)A1u, B1p, b1, h, nullptr, M_pad, 0);
  }
  // ---- layer 2 (split: utop = h@W2_top + b2, t2 = h@W2_bot) ----
  {
    dim3 grid(M_pad / 128, 2);
    gemm_mfma<<<grid, 256, 0, stream>>>(h, B2p, bias2, utop, t2b, M_pad, 1);
  }
  // ---- fused aggregate + log_softmax ----
  final_kernel<<<(N + 3) / 4, 256, 0, stream>>>((const float4*)utop, (const uint2*)t2b,
                                                offsets, ssrc, inv_deg, (float4*)out, N);
}

// Round 5
// 245.559 us; speedup vs baseline: 2.9297x; 1.1405x over previous
//
#include <hip/hip_runtime.h>
#include <cstdint>
#include <cstddef>

typedef __attribute__((ext_vector_type(8))) short bf16x8;
typedef __attribute__((ext_vector_type(4))) float f32x4;
typedef __attribute__((ext_vector_type(2))) float f32x2;

__device__ inline short bf16_rne(float f) {
  unsigned u = __builtin_bit_cast(unsigned, f);
  u += 0x7fff + ((u >> 16) & 1);
  return (short)(u >> 16);
}

__device__ inline float bf16lo(unsigned v) { return __builtin_bit_cast(float, v << 16); }
__device__ inline float bf16hi(unsigned v) { return __builtin_bit_cast(float, v & 0xffff0000u); }

__device__ inline unsigned pack2(float a, float b) {
  return ((unsigned)(unsigned short)bf16_rne(a)) | (((unsigned)(unsigned short)bf16_rne(b)) << 16);
}

__device__ inline void async_copy16(const void* g, void* l) {
  __builtin_amdgcn_global_load_lds((const __attribute__((address_space(1))) void*)g,
                                   (__attribute__((address_space(3))) void*)l, 16, 0, 0);
}

// ================= CSR build: bucketed counting sort =================
// Buckets of 256 nodes (bucket = dst >> 8). NB buckets, SB edge-chunk blocks.

__global__ __launch_bounds__(256) void bucket_hist(const int* __restrict__ dst, int E, int EPB,
                                                   int* __restrict__ histT, int SB, int NB) {
  __shared__ int h[256];
  int tid = threadIdx.x;
  h[tid] = 0;
  __syncthreads();
  int start = blockIdx.x * EPB, end = min(E, start + EPB);
  for (int i = start + tid; i < end; i += 256) atomicAdd(&h[((unsigned)dst[i]) >> 8], 1);
  __syncthreads();
  if (tid < NB) histT[tid * SB + blockIdx.x] = h[tid];
}

// hierarchical scan over M = NB*SB elements
__global__ __launch_bounds__(1024) void scan1_kernel(const int* __restrict__ in,
                                                     int* __restrict__ outx,
                                                     int* __restrict__ part, int n) {
  __shared__ int buf[1024];
  int tid = threadIdx.x;
  int i = blockIdx.x * 1024 + tid;
  int v = (i < n) ? in[i] : 0;
  buf[tid] = v;
  __syncthreads();
  #pragma unroll
  for (int off = 1; off < 1024; off <<= 1) {
    int t = (tid >= off) ? buf[tid - off] : 0;
    __syncthreads();
    buf[tid] += t;
    __syncthreads();
  }
  if (i < n) outx[i] = buf[tid] - v;
  if (tid == 1023) part[blockIdx.x] = buf[1023];
}

// scan up to 1024 partials with one 1024-thread block
__global__ __launch_bounds__(1024) void scan2_kernel(int* __restrict__ part,
                                                     int* __restrict__ outx, int n, int B) {
  __shared__ int buf[1024];
  int tid = threadIdx.x;
  int v = (tid < B) ? part[tid] : 0;
  buf[tid] = v;
  __syncthreads();
  #pragma unroll
  for (int off = 1; off < 1024; off <<= 1) {
    int t = (tid >= off) ? buf[tid - off] : 0;
    __syncthreads();
    buf[tid] += t;
    __syncthreads();
  }
  if (tid < B) part[tid] = buf[tid] - v;
  if (tid == 1023) outx[n] = buf[1023];
}

__global__ __launch_bounds__(1024) void scan3_kernel(int* __restrict__ outx,
                                                     const int* __restrict__ part, int n) {
  int i = blockIdx.x * 1024 + threadIdx.x;
  if (i < n) outx[i] += part[blockIdx.x];
}

// scatter (dst,src) pairs into bucket-grouped order
__global__ __launch_bounds__(256) void bucket_scatter(const int* __restrict__ src,
                                                      const int* __restrict__ dst, int E, int EPB,
                                                      const int* __restrict__ excl, int SB, int NB,
                                                      uint2* __restrict__ bedge) {
  __shared__ int cur[256];
  int tid = threadIdx.x;
  for (int t = tid; t < NB; t += 256) cur[t] = excl[t * SB + blockIdx.x];
  __syncthreads();
  int start = blockIdx.x * EPB, end = min(E, start + EPB);
  for (int i = start + tid; i < end; i += 256) {
    int d = dst[i];
    int p = atomicAdd(&cur[((unsigned)d) >> 8], 1);
    bedge[p] = make_uint2((unsigned)d, (unsigned)src[i]);
  }
}

// per-bucket CSR finalize
__global__ __launch_bounds__(256) void build_csr(const uint2* __restrict__ bedge,
                                                 const int* __restrict__ excl, int SB, int NB,
                                                 int N, int E,
                                                 int* __restrict__ offsets,
                                                 float* __restrict__ inv_deg,
                                                 int* __restrict__ ssrc) {
  __shared__ int buf[256];
  int b = blockIdx.x, tid = threadIdx.x;
  int estart = excl[b * SB];
  int eend = excl[(b + 1) * SB];
  buf[tid] = 0;
  __syncthreads();
  for (int i = estart + tid; i < eend; i += 256) atomicAdd(&buf[bedge[i].x & 255u], 1);
  __syncthreads();
  int cnt = buf[tid];
  #pragma unroll
  for (int off = 1; off < 256; off <<= 1) {
    int t = (tid >= off) ? buf[tid - off] : 0;
    __syncthreads();
    buf[tid] += t;
    __syncthreads();
  }
  int excl_l = buf[tid] - cnt;
  int node = (b << 8) + tid;
  if (node < N) {
    offsets[node] = estart + excl_l;
    inv_deg[node] = 1.0f / fmaxf((float)cnt, 1.0f);
  }
  if (node == N) offsets[N] = E;
  __syncthreads();
  buf[tid] = estart + excl_l;
  __syncthreads();
  for (int i = estart + tid; i < eend; i += 256) {
    uint2 e2 = bedge[i];
    int p = atomicAdd(&buf[e2.x & 255u], 1);
    ssrc[p] = (int)e2.y;
  }
}

// ================= feature pipeline =================

__global__ void convert_x_kernel(const float* __restrict__ x, unsigned* __restrict__ A1u,
                                 int npairs) {
  int idx = blockIdx.x * blockDim.x + threadIdx.x;
  if (idx < npairs) {
    int n = idx >> 6, dp = idx & 63;
    float2 v = ((const float2*)x)[idx];
    A1u[(size_t)n * 128 + dp] = pack2(v.x, v.y);
  }
}

// layer-1 aggregation: wave per node, pair-mode bf16 gather
__global__ __launch_bounds__(256) void agg1_kernel(const uint2* __restrict__ A2,
                                                   const int* __restrict__ offsets,
                                                   const int* __restrict__ ssrc,
                                                   const float* __restrict__ inv_deg,
                                                   uint2* __restrict__ A2out, int N) {
  int node = blockIdx.x * 4 + (threadIdx.x >> 6);
  if (node >= N) return;
  int lane = threadIdx.x & 63;
  int half = lane >> 5;
  int l = lane & 31;
  int s = offsets[node], e = offsets[node + 1];
  float a0 = 0.f, a1 = 0.f, a2 = 0.f, a3 = 0.f;
  int i = s;
  for (; i + 8 <= e; i += 8) {
    int sA = ssrc[i + half], sB = ssrc[i + 2 + half];
    int sC = ssrc[i + 4 + half], sD = ssrc[i + 6 + half];
    uint2 u = A2[((unsigned)sA << 6) + l];
    uint2 v = A2[((unsigned)sB << 6) + l];
    uint2 w = A2[((unsigned)sC << 6) + l];
    uint2 z = A2[((unsigned)sD << 6) + l];
    a0 += bf16lo(u.x); a1 += bf16hi(u.x); a2 += bf16lo(u.y); a3 += bf16hi(u.y);
    a0 += bf16lo(v.x); a1 += bf16hi(v.x); a2 += bf16lo(v.y); a3 += bf16hi(v.y);
    a0 += bf16lo(w.x); a1 += bf16hi(w.x); a2 += bf16lo(w.y); a3 += bf16hi(w.y);
    a0 += bf16lo(z.x); a1 += bf16hi(z.x); a2 += bf16lo(z.y); a3 += bf16hi(z.y);
  }
  for (; i + 2 <= e; i += 2) {
    int sA = ssrc[i + half];
    uint2 u = A2[((unsigned)sA << 6) + l];
    a0 += bf16lo(u.x); a1 += bf16hi(u.x); a2 += bf16lo(u.y); a3 += bf16hi(u.y);
  }
  if (i < e && half == 0) {
    uint2 u = A2[((unsigned)ssrc[i] << 6) + l];
    a0 += bf16lo(u.x); a1 += bf16hi(u.x); a2 += bf16lo(u.y); a3 += bf16hi(u.y);
  }
  a0 += __shfl_xor(a0, 32, 64);
  a1 += __shfl_xor(a1, 32, 64);
  a2 += __shfl_xor(a2, 32, 64);
  a3 += __shfl_xor(a3, 32, 64);
  if (half == 0) {
    float id = inv_deg[node];
    A2out[((unsigned)node << 6) + 32 + l] =
        make_uint2(pack2(a0 * id, a1 * id), pack2(a2 * id, a3 * id));
  }
}

// ================= weight pack + GEMM =================
__global__ void pack_w_kernel(const float* __restrict__ W, short* __restrict__ Bp, int mode) {
  int idx = blockIdx.x * 256 + threadIdx.x;
  int j = idx & 7;
  int L = (idx >> 3) & 63;
  int nt = (idx >> 9) & 15;
  int kb = idx >> 13;
  int k = kb * 32 + (L >> 4) * 8 + j;
  int n = nt * 16 + (L & 15);
  float v;
  if (mode == 0) v = W[(size_t)k * 256 + n];
  else v = (n < 128) ? W[(size_t)k * 128 + n] : W[(size_t)(256 + k) * 128 + (n - 128)];
  Bp[idx] = bf16_rne(v);
}

__global__ void bias2_kernel(const float* __restrict__ b2, float* __restrict__ bias2) {
  int j = threadIdx.x;
  bias2[j] = (j < 128) ? b2[j] : 0.0f;
}

// mode 0: out0 = bf16 relu(acc+bias) [M,256]
// mode 1: y==0 -> out0 f32 [M,128] (utop); y==1 -> out1 fp8-e4m3 [M,128] (t2)
__global__ __launch_bounds__(256) void gemm_mfma(const short* __restrict__ A,
                                                 const short* __restrict__ Bp,
                                                 const float* __restrict__ bias,
                                                 void* __restrict__ out0,
                                                 void* __restrict__ out1,
                                                 int M_pad, int mode) {
  __shared__ __align__(16) short As[4096];
  __shared__ __align__(16) short Bs[4096];
  int tid = threadIdx.x;
  int w = tid >> 6;
  int lane = tid & 63;
  int wr = w >> 1;
  int wc = w & 1;
  int bm = blockIdx.x * 128;
  int bn = blockIdx.y * 128;

  f32x4 acc[4][4];
  #pragma unroll
  for (int i = 0; i < 4; ++i)
    #pragma unroll
    for (int j = 0; j < 4; ++j) acc[i][j] = (f32x4)(0.0f);

  for (int kb = 0; kb < 8; ++kb) {
    #pragma unroll
    for (int q = 0; q < 2; ++q) {
      int f = q * 4 + w;
      int row = bm + f * 16 + (lane & 15);
      const short* g = A + (size_t)row * 256 + kb * 32 + (lane >> 4) * 8;
      async_copy16(g, &As[f * 512]);
    }
    #pragma unroll
    for (int q = 0; q < 2; ++q) {
      int f = q * 4 + w;
      const short* g = Bp + ((size_t)(kb * 16 + (bn >> 4) + f) * 64 + lane) * 8;
      async_copy16(g, &Bs[f * 512]);
    }
    __syncthreads();

    bf16x8 af[4], bfr[4];
    #pragma unroll
    for (int i = 0; i < 4; ++i)
      af[i] = *(const bf16x8*)&As[(wr * 4 + i) * 512 + lane * 8];
    #pragma unroll
    for (int j = 0; j < 4; ++j)
      bfr[j] = *(const bf16x8*)&Bs[(wc * 4 + j) * 512 + lane * 8];

    #pragma unroll
    for (int i = 0; i < 4; ++i)
      #pragma unroll
      for (int j = 0; j < 4; ++j)
        acc[i][j] = __builtin_amdgcn_mfma_f32_16x16x32_bf16(af[i], bfr[j], acc[i][j], 0, 0, 0);
    __syncthreads();
  }

  int crow0 = (lane >> 4) * 4;
  int ccol = lane & 15;
  #pragma unroll
  for (int i = 0; i < 4; ++i) {
    #pragma unroll
    for (int j = 0; j < 4; ++j) {
      int col_loc = wc * 64 + j * 16 + ccol;
      int col = bn + col_loc;
      #pragma unroll
      for (int r = 0; r < 4; ++r) {
        int row = bm + wr * 64 + i * 16 + crow0 + r;
        float v = acc[i][j][r] + bias[col];
        if (mode == 0) {
          v = fmaxf(v, 0.0f);
          ((short*)out0)[(size_t)row * 256 + col] = bf16_rne(v);
        } else if (blockIdx.y == 0) {
          ((float*)out0)[(size_t)row * 128 + col_loc] = v;
        } else {
          int pk = __builtin_amdgcn_cvt_pk_fp8_f32(v, v, 0, false);
          ((unsigned char*)out1)[(size_t)row * 128 + col_loc] = (unsigned char)(pk & 0xff);
        }
      }
    }
  }
}

// ================= fused final: aggregate fp8 t2 + utop + log_softmax =================
// t2 row = 32 dwords (128 fp8 = one 128B line). Pair-mode gather, half-wave epilogue.
__global__ __launch_bounds__(256) void final_kernel(const float4* __restrict__ utop4,
                                                    const unsigned* __restrict__ T2,
                                                    const int* __restrict__ offsets,
                                                    const int* __restrict__ ssrc,
                                                    const float* __restrict__ inv_deg,
                                                    float4* __restrict__ out4, int N) {
  int node = blockIdx.x * 4 + (threadIdx.x >> 6);
  if (node >= N) return;
  int lane = threadIdx.x & 63;
  int half = lane >> 5;
  int l = lane & 31;
  int s = offsets[node], e = offsets[node + 1];
  float a0 = 0.f, a1 = 0.f, a2 = 0.f, a3 = 0.f;
  int i = s;
  for (; i + 8 <= e; i += 8) {
    int sA = ssrc[i + half], sB = ssrc[i + 2 + half];
    int sC = ssrc[i + 4 + half], sD = ssrc[i + 6 + half];
    unsigned u = T2[((unsigned)sA << 5) + l];
    unsigned v = T2[((unsigned)sB << 5) + l];
    unsigned w = T2[((unsigned)sC << 5) + l];
    unsigned z = T2[((unsigned)sD << 5) + l];
    f32x2 p, q;
    p = __builtin_amdgcn_cvt_pk_f32_fp8(u, false); q = __builtin_amdgcn_cvt_pk_f32_fp8(u, true);
    a0 += p[0]; a1 += p[1]; a2 += q[0]; a3 += q[1];
    p = __builtin_amdgcn_cvt_pk_f32_fp8(v, false); q = __builtin_amdgcn_cvt_pk_f32_fp8(v, true);
    a0 += p[0]; a1 += p[1]; a2 += q[0]; a3 += q[1];
    p = __builtin_amdgcn_cvt_pk_f32_fp8(w, false); q = __builtin_amdgcn_cvt_pk_f32_fp8(w, true);
    a0 += p[0]; a1 += p[1]; a2 += q[0]; a3 += q[1];
    p = __builtin_amdgcn_cvt_pk_f32_fp8(z, false); q = __builtin_amdgcn_cvt_pk_f32_fp8(z, true);
    a0 += p[0]; a1 += p[1]; a2 += q[0]; a3 += q[1];
  }
  for (; i + 2 <= e; i += 2) {
    unsigned u = T2[((unsigned)ssrc[i + half] << 5) + l];
    f32x2 p = __builtin_amdgcn_cvt_pk_f32_fp8(u, false);
    f32x2 q = __builtin_amdgcn_cvt_pk_f32_fp8(u, true);
    a0 += p[0]; a1 += p[1]; a2 += q[0]; a3 += q[1];
  }
  if (i < e && half == 0) {
    unsigned u = T2[((unsigned)ssrc[i] << 5) + l];
    f32x2 p = __builtin_amdgcn_cvt_pk_f32_fp8(u, false);
    f32x2 q = __builtin_amdgcn_cvt_pk_f32_fp8(u, true);
    a0 += p[0]; a1 += p[1]; a2 += q[0]; a3 += q[1];
  }
  a0 += __shfl_xor(a0, 32, 64);
  a1 += __shfl_xor(a1, 32, 64);
  a2 += __shfl_xor(a2, 32, 64);
  a3 += __shfl_xor(a3, 32, 64);
  if (half == 0) {
    float id = inv_deg[node];
    float4 u = utop4[((unsigned)node << 5) + l];
    float v0 = u.x + a0 * id;
    float v1 = u.y + a1 * id;
    float v2 = u.z + a2 * id;
    float v3 = u.w + a3 * id;
    float m = fmaxf(fmaxf(v0, v1), fmaxf(v2, v3));
    #pragma unroll
    for (int off = 1; off < 32; off <<= 1) m = fmaxf(m, __shfl_xor(m, off, 32));
    float su = expf(v0 - m) + expf(v1 - m) + expf(v2 - m) + expf(v3 - m);
    #pragma unroll
    for (int off = 1; off < 32; off <<= 1) su += __shfl_xor(su, off, 32);
    float ls = m + logf(su);
    out4[((unsigned)node << 5) + l] = make_float4(v0 - ls, v1 - ls, v2 - ls, v3 - ls);
  }
}

extern "C" void kernel_launch(void* const* d_in, const int* in_sizes, int n_in,
                              void* d_out, int out_size, void* d_ws, size_t ws_size,
                              hipStream_t stream) {
  const float* x        = (const float*)d_in[0];
  const int*   edge_src = (const int*)d_in[1];
  const int*   edge_dst = (const int*)d_in[2];
  const float* W1       = (const float*)d_in[3];
  const float* b1       = (const float*)d_in[4];
  const float* W2       = (const float*)d_in[5];
  const float* b2       = (const float*)d_in[6];
  float* out = (float*)d_out;

  const int D_IN = 128;
  const int N = in_sizes[0] / D_IN;
  const int E = in_sizes[1];
  const int M_pad = ((N + 127) / 128) * 128;

  const int SB = 1024;                   // edge-chunk blocks (occupancy!)
  const int EPB = (E + SB - 1) / SB;     // edges per chunk (~782)
  const int NB = (N + 255) >> 8;         // node buckets (256 nodes each)
  const int M = NB * SB;                 // hist matrix size
  const int sbl = (M + 1023) / 1024;     // scan blocks (<= 1024)

  char* ws = (char*)d_ws;
  size_t p = 0;
  auto take = [&](size_t bytes) -> size_t {
    size_t r = p;
    p += (bytes + 255) & ~(size_t)255;
    return r;
  };
  size_t histT_off = take((size_t)M * 4);
  size_t excl_off  = take((size_t)(M + 1) * 4);
  size_t part_off  = take((size_t)1024 * 4);
  size_t bedge_off = take((size_t)E * 8);
  size_t offs_off  = take((size_t)(N + 1) * 4);
  size_t inv_off   = take((size_t)N * 4);
  size_t ssrc_off  = take((size_t)E * 4);
  size_t A1_off    = take((size_t)M_pad * 256 * 2);   // bf16 [x | agg1]
  size_t h_off     = take((size_t)M_pad * 256 * 2);   // bf16 h
  size_t B1p_off   = take((size_t)256 * 256 * 2);
  size_t B2p_off   = take((size_t)256 * 256 * 2);
  size_t bias2_off = take((size_t)256 * 4);
  size_t utop_off  = take((size_t)M_pad * 128 * 4);   // f32
  size_t t2_off    = take((size_t)M_pad * 128);       // fp8
  (void)ws_size;

  int*   histT   = (int*)(ws + histT_off);
  int*   excl    = (int*)(ws + excl_off);
  int*   part    = (int*)(ws + part_off);
  uint2* bedge   = (uint2*)(ws + bedge_off);
  int*   offsets = (int*)(ws + offs_off);
  float* inv_deg = (float*)(ws + inv_off);
  int*   ssrc    = (int*)(ws + ssrc_off);
  unsigned* A1u  = (unsigned*)(ws + A1_off);
  short* h       = (short*)(ws + h_off);
  short* B1p     = (short*)(ws + B1p_off);
  short* B2p     = (short*)(ws + B2p_off);
  float* bias2   = (float*)(ws + bias2_off);
  float* utop    = (float*)(ws + utop_off);
  unsigned char* t2f8 = (unsigned char*)(ws + t2_off);

  // ---- CSR build ----
  bucket_hist<<<SB, 256, 0, stream>>>(edge_dst, E, EPB, histT, SB, NB);
  scan1_kernel<<<sbl, 1024, 0, stream>>>(histT, excl, part, M);
  scan2_kernel<<<1, 1024, 0, stream>>>(part, excl, M, sbl);
  scan3_kernel<<<sbl, 1024, 0, stream>>>(excl, part, M);
  bucket_scatter<<<SB, 256, 0, stream>>>(edge_src, edge_dst, E, EPB, excl, SB, NB, bedge);
  build_csr<<<NB, 256, 0, stream>>>(bedge, excl, SB, NB, N, E, offsets, inv_deg, ssrc);

  // ---- weights / conversions ----
  pack_w_kernel<<<256, 256, 0, stream>>>(W1, B1p, 0);
  pack_w_kernel<<<256, 256, 0, stream>>>(W2, B2p, 1);
  bias2_kernel<<<1, 256, 0, stream>>>(b2, bias2);
  convert_x_kernel<<<(N * 64 + 255) / 256, 256, 0, stream>>>(x, A1u, N * 64);

  // ---- layer 1 ----
  agg1_kernel<<<(N + 3) / 4, 256, 0, stream>>>((const uint2*)A1u, offsets, ssrc, inv_deg,
                                               (uint2*)A1u, N);
  {
    dim3 grid(M_pad / 128, 2);
    gemm_mfma<<<grid, 256, 0, stream>>>((const short*)A1u, B1p, b1, h, nullptr, M_pad, 0);
  }
  // ---- layer 2 (split: utop = h@W2_top + b2, t2 = h@W2_bot in fp8) ----
  {
    dim3 grid(M_pad / 128, 2);
    gemm_mfma<<<grid, 256, 0, stream>>>(h, B2p, bias2, utop, t2f8, M_pad, 1);
  }
  // ---- fused aggregate + log_softmax ----
  final_kernel<<<(N + 3) / 4, 256, 0, stream>>>((const float4*)utop, (const unsigned*)t2f8,
                                                offsets, ssrc, inv_deg, (float4*)out, N);
}

// Round 6
// 240.197 us; speedup vs baseline: 2.9951x; 1.0223x over previous
//
#include <hip/hip_runtime.h>
#include <cstdint>
#include <cstddef>

typedef __attribute__((ext_vector_type(8))) short bf16x8;
typedef __attribute__((ext_vector_type(4))) float f32x4;
typedef __attribute__((ext_vector_type(2))) float f32x2;

__device__ inline short bf16_rne(float f) {
  unsigned u = __builtin_bit_cast(unsigned, f);
  u += 0x7fff + ((u >> 16) & 1);
  return (short)(u >> 16);
}

__device__ inline float bf16lo(unsigned v) { return __builtin_bit_cast(float, v << 16); }
__device__ inline float bf16hi(unsigned v) { return __builtin_bit_cast(float, v & 0xffff0000u); }

__device__ inline unsigned pack2(float a, float b) {
  return ((unsigned)(unsigned short)bf16_rne(a)) | (((unsigned)(unsigned short)bf16_rne(b)) << 16);
}

__device__ inline void async_copy16(const void* g, void* l) {
  __builtin_amdgcn_global_load_lds((const __attribute__((address_space(1))) void*)g,
                                   (__attribute__((address_space(3))) void*)l, 16, 0, 0);
}

// ================= CSR build: bucketed counting sort =================
// Buckets of 256 nodes (bucket = dst >> 8). NB buckets, SB=1024 edge-chunk blocks.
// bedge packs (dst&255)<<24 | src  (src < 2^24).

__global__ __launch_bounds__(256) void bucket_hist(const int* __restrict__ dst, int E, int EPB,
                                                   int* __restrict__ histT, int SB, int NB) {
  __shared__ int h[256];
  int tid = threadIdx.x;
  h[tid] = 0;
  __syncthreads();
  int start = blockIdx.x * EPB, end = min(E, start + EPB);
  for (int i = start + tid; i < end; i += 256) atomicAdd(&h[((unsigned)dst[i]) >> 8], 1);
  __syncthreads();
  if (tid < NB) histT[tid * SB + blockIdx.x] = h[tid];
}

// hierarchical scan over M = NB*SB elements (part add folded into consumers)
__global__ __launch_bounds__(1024) void scan1_kernel(const int* __restrict__ in,
                                                     int* __restrict__ outx,
                                                     int* __restrict__ part, int n) {
  __shared__ int buf[1024];
  int tid = threadIdx.x;
  int i = blockIdx.x * 1024 + tid;
  int v = (i < n) ? in[i] : 0;
  buf[tid] = v;
  __syncthreads();
  #pragma unroll
  for (int off = 1; off < 1024; off <<= 1) {
    int t = (tid >= off) ? buf[tid - off] : 0;
    __syncthreads();
    buf[tid] += t;
    __syncthreads();
  }
  if (i < n) outx[i] = buf[tid] - v;
  if (tid == 1023) part[blockIdx.x] = buf[1023];
}

// scan up to 1024 partials with one 1024-thread block (in place, exclusive)
__global__ __launch_bounds__(1024) void scan2_kernel(int* __restrict__ part, int B) {
  __shared__ int buf[1024];
  int tid = threadIdx.x;
  int v = (tid < B) ? part[tid] : 0;
  buf[tid] = v;
  __syncthreads();
  #pragma unroll
  for (int off = 1; off < 1024; off <<= 1) {
    int t = (tid >= off) ? buf[tid - off] : 0;
    __syncthreads();
    buf[tid] += t;
    __syncthreads();
  }
  if (tid < B) part[tid] = buf[tid] - v;
}

// scatter packed (dst&255,src) into bucket-grouped order
__global__ __launch_bounds__(256) void bucket_scatter(const int* __restrict__ src,
                                                      const int* __restrict__ dst, int E, int EPB,
                                                      const int* __restrict__ excl,
                                                      const int* __restrict__ part, int SB, int NB,
                                                      unsigned* __restrict__ bedge) {
  __shared__ int cur[256];
  int tid = threadIdx.x;
  // histT index t*SB + blk; since SB=1024 the scan1-block of that index is exactly t.
  for (int t = tid; t < NB; t += 256) cur[t] = excl[t * SB + blockIdx.x] + part[t];
  __syncthreads();
  int start = blockIdx.x * EPB, end = min(E, start + EPB);
  for (int i = start + tid; i < end; i += 256) {
    unsigned d = (unsigned)dst[i];
    int p = atomicAdd(&cur[d >> 8], 1);
    bedge[p] = ((d & 255u) << 24) | (unsigned)src[i];
  }
}

// per-bucket CSR finalize
__global__ __launch_bounds__(256) void build_csr(const unsigned* __restrict__ bedge,
                                                 const int* __restrict__ excl,
                                                 const int* __restrict__ part, int SB, int NB,
                                                 int N, int E,
                                                 int* __restrict__ offsets,
                                                 float* __restrict__ inv_deg,
                                                 int* __restrict__ ssrc) {
  __shared__ int buf[256];
  int b = blockIdx.x, tid = threadIdx.x;
  int estart = excl[b * SB] + part[b];
  int eend = (b == NB - 1) ? E : (excl[(b + 1) * SB] + part[b + 1]);
  buf[tid] = 0;
  __syncthreads();
  for (int i = estart + tid; i < eend; i += 256) atomicAdd(&buf[bedge[i] >> 24], 1);
  __syncthreads();
  int cnt = buf[tid];
  #pragma unroll
  for (int off = 1; off < 256; off <<= 1) {
    int t = (tid >= off) ? buf[tid - off] : 0;
    __syncthreads();
    buf[tid] += t;
    __syncthreads();
  }
  int excl_l = buf[tid] - cnt;
  int node = (b << 8) + tid;
  if (node < N) {
    offsets[node] = estart + excl_l;
    inv_deg[node] = 1.0f / fmaxf((float)cnt, 1.0f);
  }
  if (node == N) offsets[N] = E;
  __syncthreads();
  buf[tid] = estart + excl_l;
  __syncthreads();
  for (int i = estart + tid; i < eend; i += 256) {
    unsigned e2 = bedge[i];
    int p = atomicAdd(&buf[e2 >> 24], 1);
    ssrc[p] = (int)(e2 & 0xFFFFFFu);
  }
}

// ================= fused prep: pack W1/W2, bias2, convert x -> bf16 =================
__global__ __launch_bounds__(256) void prep_kernel(const float* __restrict__ W1,
                                                   const float* __restrict__ W2,
                                                   const float* __restrict__ b2,
                                                   const float* __restrict__ x,
                                                   short* __restrict__ B1p,
                                                   short* __restrict__ B2p,
                                                   float* __restrict__ bias2,
                                                   unsigned* __restrict__ A1u, int npairs) {
  int b = blockIdx.x;
  if (b < 512) {
    int mode = b >> 8;
    int idx = (b & 255) * 256 + threadIdx.x;  // 65536 per weight
    int j = idx & 7;
    int L = (idx >> 3) & 63;
    int nt = (idx >> 9) & 15;
    int kb = idx >> 13;
    int k = kb * 32 + (L >> 4) * 8 + j;
    int n = nt * 16 + (L & 15);
    if (mode == 0) {
      B1p[idx] = bf16_rne(W1[(size_t)k * 256 + n]);
    } else {
      float v = (n < 128) ? W2[(size_t)k * 128 + n] : W2[(size_t)(256 + k) * 128 + (n - 128)];
      B2p[idx] = bf16_rne(v);
    }
  } else if (b == 512) {
    int j = threadIdx.x;
    bias2[j] = (j < 128) ? b2[j] : 0.0f;
  } else {
    int idx = (b - 513) * 256 + threadIdx.x;
    if (idx < npairs) {
      int n = idx >> 6, dp = idx & 63;
      float2 v = ((const float2*)x)[idx];
      A1u[(size_t)n * 128 + dp] = pack2(v.x, v.y);
    }
  }
}

// ================= layer-1 aggregation: wave per node, pair-mode bf16 gather =========
__global__ __launch_bounds__(256) void agg1_kernel(const uint2* __restrict__ A2,
                                                   const int* __restrict__ offsets,
                                                   const int* __restrict__ ssrc,
                                                   const float* __restrict__ inv_deg,
                                                   uint2* __restrict__ A2out, int N) {
  int node = blockIdx.x * 4 + (threadIdx.x >> 6);
  if (node >= N) return;
  int lane = threadIdx.x & 63;
  int half = lane >> 5;
  int l = lane & 31;
  int s = offsets[node], e = offsets[node + 1];
  float a0 = 0.f, a1 = 0.f, a2 = 0.f, a3 = 0.f;
  int i = s;
  for (; i + 8 <= e; i += 8) {
    int sA = ssrc[i + half], sB = ssrc[i + 2 + half];
    int sC = ssrc[i + 4 + half], sD = ssrc[i + 6 + half];
    uint2 u = A2[((unsigned)sA << 6) + l];
    uint2 v = A2[((unsigned)sB << 6) + l];
    uint2 w = A2[((unsigned)sC << 6) + l];
    uint2 z = A2[((unsigned)sD << 6) + l];
    a0 += bf16lo(u.x); a1 += bf16hi(u.x); a2 += bf16lo(u.y); a3 += bf16hi(u.y);
    a0 += bf16lo(v.x); a1 += bf16hi(v.x); a2 += bf16lo(v.y); a3 += bf16hi(v.y);
    a0 += bf16lo(w.x); a1 += bf16hi(w.x); a2 += bf16lo(w.y); a3 += bf16hi(w.y);
    a0 += bf16lo(z.x); a1 += bf16hi(z.x); a2 += bf16lo(z.y); a3 += bf16hi(z.y);
  }
  for (; i + 2 <= e; i += 2) {
    int sA = ssrc[i + half];
    uint2 u = A2[((unsigned)sA << 6) + l];
    a0 += bf16lo(u.x); a1 += bf16hi(u.x); a2 += bf16lo(u.y); a3 += bf16hi(u.y);
  }
  if (i < e && half == 0) {
    uint2 u = A2[((unsigned)ssrc[i] << 6) + l];
    a0 += bf16lo(u.x); a1 += bf16hi(u.x); a2 += bf16lo(u.y); a3 += bf16hi(u.y);
  }
  a0 += __shfl_xor(a0, 32, 64);
  a1 += __shfl_xor(a1, 32, 64);
  a2 += __shfl_xor(a2, 32, 64);
  a3 += __shfl_xor(a3, 32, 64);
  if (half == 0) {
    float id = inv_deg[node];
    A2out[((unsigned)node << 6) + 32 + l] =
        make_uint2(pack2(a0 * id, a1 * id), pack2(a2 * id, a3 * id));
  }
}

// ================= bf16 MFMA GEMM =================
// mode 0: out0 = bf16 relu(acc+bias) [M,256]
// mode 1: y==0 -> out0 bf16 [M,128] (utop); y==1 -> out1 fp8-e4m3 [M,128] (t2)
__global__ __launch_bounds__(256) void gemm_mfma(const short* __restrict__ A,
                                                 const short* __restrict__ Bp,
                                                 const float* __restrict__ bias,
                                                 void* __restrict__ out0,
                                                 void* __restrict__ out1,
                                                 int M_pad, int mode) {
  __shared__ __align__(16) short As[4096];
  __shared__ __align__(16) short Bs[4096];
  int tid = threadIdx.x;
  int w = tid >> 6;
  int lane = tid & 63;
  int wr = w >> 1;
  int wc = w & 1;
  int bm = blockIdx.x * 128;
  int bn = blockIdx.y * 128;

  f32x4 acc[4][4];
  #pragma unroll
  for (int i = 0; i < 4; ++i)
    #pragma unroll
    for (int j = 0; j < 4; ++j) acc[i][j] = (f32x4)(0.0f);

  for (int kb = 0; kb < 8; ++kb) {
    #pragma unroll
    for (int q = 0; q < 2; ++q) {
      int f = q * 4 + w;
      int row = bm + f * 16 + (lane & 15);
      const short* g = A + (size_t)row * 256 + kb * 32 + (lane >> 4) * 8;
      async_copy16(g, &As[f * 512]);
    }
    #pragma unroll
    for (int q = 0; q < 2; ++q) {
      int f = q * 4 + w;
      const short* g = Bp + ((size_t)(kb * 16 + (bn >> 4) + f) * 64 + lane) * 8;
      async_copy16(g, &Bs[f * 512]);
    }
    __syncthreads();

    bf16x8 af[4], bfr[4];
    #pragma unroll
    for (int i = 0; i < 4; ++i)
      af[i] = *(const bf16x8*)&As[(wr * 4 + i) * 512 + lane * 8];
    #pragma unroll
    for (int j = 0; j < 4; ++j)
      bfr[j] = *(const bf16x8*)&Bs[(wc * 4 + j) * 512 + lane * 8];

    #pragma unroll
    for (int i = 0; i < 4; ++i)
      #pragma unroll
      for (int j = 0; j < 4; ++j)
        acc[i][j] = __builtin_amdgcn_mfma_f32_16x16x32_bf16(af[i], bfr[j], acc[i][j], 0, 0, 0);
    __syncthreads();
  }

  int crow0 = (lane >> 4) * 4;
  int ccol = lane & 15;
  #pragma unroll
  for (int i = 0; i < 4; ++i) {
    #pragma unroll
    for (int j = 0; j < 4; ++j) {
      int col_loc = wc * 64 + j * 16 + ccol;
      int col = bn + col_loc;
      #pragma unroll
      for (int r = 0; r < 4; ++r) {
        int row = bm + wr * 64 + i * 16 + crow0 + r;
        float v = acc[i][j][r] + bias[col];
        if (mode == 0) {
          v = fmaxf(v, 0.0f);
          ((short*)out0)[(size_t)row * 256 + col] = bf16_rne(v);
        } else if (blockIdx.y == 0) {
          ((short*)out0)[(size_t)row * 128 + col_loc] = bf16_rne(v);
        } else {
          int pk = __builtin_amdgcn_cvt_pk_fp8_f32(v, v, 0, false);
          ((unsigned char*)out1)[(size_t)row * 128 + col_loc] = (unsigned char)(pk & 0xff);
        }
      }
    }
  }
}

// ================= fused final: aggregate fp8 t2 + bf16 utop + log_softmax ===========
__global__ __launch_bounds__(256) void final_kernel(const uint2* __restrict__ utopU,
                                                    const unsigned* __restrict__ T2,
                                                    const int* __restrict__ offsets,
                                                    const int* __restrict__ ssrc,
                                                    const float* __restrict__ inv_deg,
                                                    float4* __restrict__ out4, int N) {
  int node = blockIdx.x * 4 + (threadIdx.x >> 6);
  if (node >= N) return;
  int lane = threadIdx.x & 63;
  int half = lane >> 5;
  int l = lane & 31;
  int s = offsets[node], e = offsets[node + 1];
  float a0 = 0.f, a1 = 0.f, a2 = 0.f, a3 = 0.f;
  int i = s;
  for (; i + 8 <= e; i += 8) {
    int sA = ssrc[i + half], sB = ssrc[i + 2 + half];
    int sC = ssrc[i + 4 + half], sD = ssrc[i + 6 + half];
    unsigned u = T2[((unsigned)sA << 5) + l];
    unsigned v = T2[((unsigned)sB << 5) + l];
    unsigned w = T2[((unsigned)sC << 5) + l];
    unsigned z = T2[((unsigned)sD << 5) + l];
    f32x2 p, q;
    p = __builtin_amdgcn_cvt_pk_f32_fp8(u, false); q = __builtin_amdgcn_cvt_pk_f32_fp8(u, true);
    a0 += p[0]; a1 += p[1]; a2 += q[0]; a3 += q[1];
    p = __builtin_amdgcn_cvt_pk_f32_fp8(v, false); q = __builtin_amdgcn_cvt_pk_f32_fp8(v, true);
    a0 += p[0]; a1 += p[1]; a2 += q[0]; a3 += q[1];
    p = __builtin_amdgcn_cvt_pk_f32_fp8(w, false); q = __builtin_amdgcn_cvt_pk_f32_fp8(w, true);
    a0 += p[0]; a1 += p[1]; a2 += q[0]; a3 += q[1];
    p = __builtin_amdgcn_cvt_pk_f32_fp8(z, false); q = __builtin_amdgcn_cvt_pk_f32_fp8(z, true);
    a0 += p[0]; a1 += p[1]; a2 += q[0]; a3 += q[1];
  }
  for (; i + 2 <= e; i += 2) {
    unsigned u = T2[((unsigned)ssrc[i + half] << 5) + l];
    f32x2 p = __builtin_amdgcn_cvt_pk_f32_fp8(u, false);
    f32x2 q = __builtin_amdgcn_cvt_pk_f32_fp8(u, true);
    a0 += p[0]; a1 += p[1]; a2 += q[0]; a3 += q[1];
  }
  if (i < e && half == 0) {
    unsigned u = T2[((unsigned)ssrc[i] << 5) + l];
    f32x2 p = __builtin_amdgcn_cvt_pk_f32_fp8(u, false);
    f32x2 q = __builtin_amdgcn_cvt_pk_f32_fp8(u, true);
    a0 += p[0]; a1 += p[1]; a2 += q[0]; a3 += q[1];
  }
  a0 += __shfl_xor(a0, 32, 64);
  a1 += __shfl_xor(a1, 32, 64);
  a2 += __shfl_xor(a2, 32, 64);
  a3 += __shfl_xor(a3, 32, 64);
  if (half == 0) {
    float id = inv_deg[node];
    uint2 u = utopU[((unsigned)node << 5) + l];
    float v0 = bf16lo(u.x) + a0 * id;
    float v1 = bf16hi(u.x) + a1 * id;
    float v2 = bf16lo(u.y) + a2 * id;
    float v3 = bf16hi(u.y) + a3 * id;
    float m = fmaxf(fmaxf(v0, v1), fmaxf(v2, v3));
    #pragma unroll
    for (int off = 1; off < 32; off <<= 1) m = fmaxf(m, __shfl_xor(m, off, 32));
    float su = expf(v0 - m) + expf(v1 - m) + expf(v2 - m) + expf(v3 - m);
    #pragma unroll
    for (int off = 1; off < 32; off <<= 1) su += __shfl_xor(su, off, 32);
    float ls = m + logf(su);
    out4[((unsigned)node << 5) + l] = make_float4(v0 - ls, v1 - ls, v2 - ls, v3 - ls);
  }
}

extern "C" void kernel_launch(void* const* d_in, const int* in_sizes, int n_in,
                              void* d_out, int out_size, void* d_ws, size_t ws_size,
                              hipStream_t stream) {
  const float* x        = (const float*)d_in[0];
  const int*   edge_src = (const int*)d_in[1];
  const int*   edge_dst = (const int*)d_in[2];
  const float* W1       = (const float*)d_in[3];
  const float* b1       = (const float*)d_in[4];
  const float* W2       = (const float*)d_in[5];
  const float* b2       = (const float*)d_in[6];
  float* out = (float*)d_out;

  const int D_IN = 128;
  const int N = in_sizes[0] / D_IN;
  const int E = in_sizes[1];
  const int M_pad = ((N + 127) / 128) * 128;

  const int SB = 1024;                   // edge-chunk blocks
  const int EPB = (E + SB - 1) / SB;     // edges per chunk
  const int NB = (N + 255) >> 8;         // node buckets
  const int M = NB * SB;                 // hist matrix size (scan1 blocks = NB exactly)
  const int sbl = (M + 1023) / 1024;     // == NB

  char* ws = (char*)d_ws;
  size_t p = 0;
  auto take = [&](size_t bytes) -> size_t {
    size_t r = p;
    p += (bytes + 255) & ~(size_t)255;
    return r;
  };
  size_t histT_off = take((size_t)M * 4);
  size_t excl_off  = take((size_t)(M + 1) * 4);
  size_t part_off  = take((size_t)1024 * 4);
  size_t bedge_off = take((size_t)E * 4);             // packed 4B/edge
  size_t offs_off  = take((size_t)(N + 1) * 4);
  size_t inv_off   = take((size_t)N * 4);
  size_t ssrc_off  = take((size_t)E * 4);
  size_t A1_off    = take((size_t)M_pad * 256 * 2);   // bf16 [x | agg1]
  size_t h_off     = take((size_t)M_pad * 256 * 2);   // bf16 h
  size_t B1p_off   = take((size_t)256 * 256 * 2);
  size_t B2p_off   = take((size_t)256 * 256 * 2);
  size_t bias2_off = take((size_t)256 * 4);
  size_t utop_off  = take((size_t)M_pad * 128 * 2);   // bf16
  size_t t2_off    = take((size_t)M_pad * 128);       // fp8
  (void)ws_size;

  int*   histT   = (int*)(ws + histT_off);
  int*   excl    = (int*)(ws + excl_off);
  int*   part    = (int*)(ws + part_off);
  unsigned* bedge = (unsigned*)(ws + bedge_off);
  int*   offsets = (int*)(ws + offs_off);
  float* inv_deg = (float*)(ws + inv_off);
  int*   ssrc    = (int*)(ws + ssrc_off);
  unsigned* A1u  = (unsigned*)(ws + A1_off);
  short* h       = (short*)(ws + h_off);
  short* B1p     = (short*)(ws + B1p_off);
  short* B2p     = (short*)(ws + B2p_off);
  float* bias2   = (float*)(ws + bias2_off);
  short* utop    = (short*)(ws + utop_off);
  unsigned char* t2f8 = (unsigned char*)(ws + t2_off);

  // ---- CSR build (scan3 folded into bucket_scatter/build_csr via part[]) ----
  bucket_hist<<<SB, 256, 0, stream>>>(edge_dst, E, EPB, histT, SB, NB);
  scan1_kernel<<<sbl, 1024, 0, stream>>>(histT, excl, part, M);
  scan2_kernel<<<1, 1024, 0, stream>>>(part, sbl);
  bucket_scatter<<<SB, 256, 0, stream>>>(edge_src, edge_dst, E, EPB, excl, part, SB, NB, bedge);
  build_csr<<<NB, 256, 0, stream>>>(bedge, excl, part, SB, NB, N, E, offsets, inv_deg, ssrc);

  // ---- fused prep: pack weights, bias2, convert x ----
  {
    int npairs = N * 64;
    int grid = 513 + (npairs + 255) / 256;
    prep_kernel<<<grid, 256, 0, stream>>>(W1, W2, b2, x, B1p, B2p, bias2, A1u, npairs);
  }

  // ---- layer 1 ----
  agg1_kernel<<<(N + 3) / 4, 256, 0, stream>>>((const uint2*)A1u, offsets, ssrc, inv_deg,
                                               (uint2*)A1u, N);
  {
    dim3 grid(M_pad / 128, 2);
    gemm_mfma<<<grid, 256, 0, stream>>>((const short*)A1u, B1p, b1, h, nullptr, M_pad, 0);
  }
  // ---- layer 2 (split: utop = bf16(h@W2_top + b2), t2 = fp8(h@W2_bot)) ----
  {
    dim3 grid(M_pad / 128, 2);
    gemm_mfma<<<grid, 256, 0, stream>>>(h, B2p, bias2, utop, t2f8, M_pad, 1);
  }
  // ---- fused aggregate + log_softmax ----
  final_kernel<<<(N + 3) / 4, 256, 0, stream>>>((const uint2*)utop, (const unsigned*)t2f8,
                                                offsets, ssrc, inv_deg, (float4*)out, N);
}

// Round 7
// 236.852 us; speedup vs baseline: 3.0374x; 1.0141x over previous
//
#include <hip/hip_runtime.h>
#include <cstdint>
#include <cstddef>

typedef __attribute__((ext_vector_type(8))) short bf16x8;
typedef __attribute__((ext_vector_type(4))) float f32x4;
typedef __attribute__((ext_vector_type(2))) float f32x2;

__device__ inline short bf16_rne(float f) {
  unsigned u = __builtin_bit_cast(unsigned, f);
  u += 0x7fff + ((u >> 16) & 1);
  return (short)(u >> 16);
}

__device__ inline float bf16lo(unsigned v) { return __builtin_bit_cast(float, v << 16); }
__device__ inline float bf16hi(unsigned v) { return __builtin_bit_cast(float, v & 0xffff0000u); }

__device__ inline unsigned pack2(float a, float b) {
  return ((unsigned)(unsigned short)bf16_rne(a)) | (((unsigned)(unsigned short)bf16_rne(b)) << 16);
}

__device__ inline void async_copy16(const void* g, void* l) {
  __builtin_amdgcn_global_load_lds((const __attribute__((address_space(1))) void*)g,
                                   (__attribute__((address_space(3))) void*)l, 16, 0, 0);
}

// ================= CSR build: bucketed counting sort =================
// Buckets of 128 nodes (bucket = dst >> 7). NB buckets, SB=1024 edge-chunk blocks.
// bedge packs (dst&127)<<24 | src  (src < 2^24).

__global__ __launch_bounds__(256) void bucket_hist(const int* __restrict__ dst, int E, int EPB,
                                                   int* __restrict__ histT, int SB, int NB) {
  __shared__ int h[512];
  int tid = threadIdx.x;
  for (int t = tid; t < NB; t += 256) h[t] = 0;
  __syncthreads();
  int start = blockIdx.x * EPB, end = min(E, start + EPB);
  for (int i = start + tid; i < end; i += 256) atomicAdd(&h[((unsigned)dst[i]) >> 7], 1);
  __syncthreads();
  for (int t = tid; t < NB; t += 256) histT[t * SB + blockIdx.x] = h[t];
}

// hierarchical scan over M = NB*SB elements (chunk t == bucket t since SB==1024)
__global__ __launch_bounds__(1024) void scan1_kernel(const int* __restrict__ in,
                                                     int* __restrict__ outx,
                                                     int* __restrict__ part, int n) {
  __shared__ int buf[1024];
  int tid = threadIdx.x;
  int i = blockIdx.x * 1024 + tid;
  int v = (i < n) ? in[i] : 0;
  buf[tid] = v;
  __syncthreads();
  #pragma unroll
  for (int off = 1; off < 1024; off <<= 1) {
    int t = (tid >= off) ? buf[tid - off] : 0;
    __syncthreads();
    buf[tid] += t;
    __syncthreads();
  }
  if (i < n) outx[i] = buf[tid] - v;
  if (tid == 1023) part[blockIdx.x] = buf[1023];
}

// scan up to 1024 partials with one block (in place, exclusive)
__global__ __launch_bounds__(1024) void scan2_kernel(int* __restrict__ part, int B) {
  __shared__ int buf[1024];
  int tid = threadIdx.x;
  int v = (tid < B) ? part[tid] : 0;
  buf[tid] = v;
  __syncthreads();
  #pragma unroll
  for (int off = 1; off < 1024; off <<= 1) {
    int t = (tid >= off) ? buf[tid - off] : 0;
    __syncthreads();
    buf[tid] += t;
    __syncthreads();
  }
  if (tid < B) part[tid] = buf[tid] - v;
}

// scatter packed (dst&127,src) into bucket-grouped order
__global__ __launch_bounds__(256) void bucket_scatter(const int* __restrict__ src,
                                                      const int* __restrict__ dst, int E, int EPB,
                                                      const int* __restrict__ excl,
                                                      const int* __restrict__ part, int SB, int NB,
                                                      unsigned* __restrict__ bedge) {
  __shared__ int cur[512];
  int tid = threadIdx.x;
  for (int t = tid; t < NB; t += 256) cur[t] = excl[t * SB + blockIdx.x] + part[t];
  __syncthreads();
  int start = blockIdx.x * EPB, end = min(E, start + EPB);
  for (int i = start + tid; i < end; i += 256) {
    unsigned d = (unsigned)dst[i];
    int p = atomicAdd(&cur[d >> 7], 1);
    bedge[p] = ((d & 127u) << 24) | (unsigned)src[i];
  }
}

// per-bucket CSR finalize (128 nodes per bucket)
__global__ __launch_bounds__(256) void build_csr(const unsigned* __restrict__ bedge,
                                                 const int* __restrict__ excl,
                                                 const int* __restrict__ part, int SB, int NB,
                                                 int N, int E,
                                                 int* __restrict__ offsets,
                                                 float* __restrict__ inv_deg,
                                                 int* __restrict__ ssrc) {
  __shared__ int buf[128];
  int b = blockIdx.x, tid = threadIdx.x;
  int estart = excl[b * SB] + part[b];
  int eend = (b == NB - 1) ? E : (excl[(b + 1) * SB] + part[b + 1]);
  if (tid < 128) buf[tid] = 0;
  __syncthreads();
  for (int i = estart + tid; i < eend; i += 256) atomicAdd(&buf[bedge[i] >> 24], 1);
  __syncthreads();
  int cnt = (tid < 128) ? buf[tid] : 0;
  #pragma unroll
  for (int off = 1; off < 128; off <<= 1) {
    int t = (tid >= off && tid < 128) ? buf[tid - off] : 0;
    __syncthreads();
    if (tid < 128) buf[tid] += t;
    __syncthreads();
  }
  if (tid < 128) {
    int excl_l = buf[tid] - cnt;
    int node = (b << 7) + tid;
    if (node < N) {
      offsets[node] = estart + excl_l;
      inv_deg[node] = 1.0f / fmaxf((float)cnt, 1.0f);
    }
    if (node == N) offsets[N] = E;
    buf[tid] = estart + excl_l;  // cursor
  }
  __syncthreads();
  for (int i = estart + tid; i < eend; i += 256) {
    unsigned e2 = bedge[i];
    int p = atomicAdd(&buf[e2 >> 24], 1);
    ssrc[p] = (int)(e2 & 0xFFFFFFu);
  }
}

// ================= fused prep: pack W1/W2, bias2, convert x -> bf16 + fp8 ============
__global__ __launch_bounds__(256) void prep_kernel(const float* __restrict__ W1,
                                                   const float* __restrict__ W2,
                                                   const float* __restrict__ b2,
                                                   const float* __restrict__ x,
                                                   short* __restrict__ B1p,
                                                   short* __restrict__ B2p,
                                                   float* __restrict__ bias2,
                                                   unsigned* __restrict__ A1u,
                                                   unsigned* __restrict__ xf8, int nquads) {
  int b = blockIdx.x;
  if (b < 512) {
    int mode = b >> 8;
    int idx = (b & 255) * 256 + threadIdx.x;  // 65536 per weight
    int j = idx & 7;
    int L = (idx >> 3) & 63;
    int nt = (idx >> 9) & 15;
    int kb = idx >> 13;
    int k = kb * 32 + (L >> 4) * 8 + j;
    int n = nt * 16 + (L & 15);
    if (mode == 0) {
      B1p[idx] = bf16_rne(W1[(size_t)k * 256 + n]);
    } else {
      float v = (n < 128) ? W2[(size_t)k * 128 + n] : W2[(size_t)(256 + k) * 128 + (n - 128)];
      B2p[idx] = bf16_rne(v);
    }
  } else if (b == 512) {
    int j = threadIdx.x;
    bias2[j] = (j < 128) ? b2[j] : 0.0f;
  } else {
    int idx = (b - 513) * 256 + threadIdx.x;  // quad of 4 floats
    if (idx < nquads) {
      int n = idx >> 5, q = idx & 31;
      float4 v = ((const float4*)x)[idx];
      // bf16 left half of A (row = 128 uints; left half = 64)
      ((uint2*)A1u)[(size_t)n * 64 + q] = make_uint2(pack2(v.x, v.y), pack2(v.z, v.w));
      // fp8 gather table (row = 32 uints)
      int pk = __builtin_amdgcn_cvt_pk_fp8_f32(v.x, v.y, 0, false);
      pk = __builtin_amdgcn_cvt_pk_fp8_f32(v.z, v.w, pk, true);
      xf8[(size_t)n * 32 + q] = (unsigned)pk;
    }
  }
}

// ================= quad-mode fp8 gather helpers =================
// table row = 128 B = 16 uint2; 16 lanes per edge, lane l holds dims l*8..l*8+7.

// layer-1 aggregation: wave per node, writes bf16 into A1 right half
__global__ __launch_bounds__(256) void agg1_kernel(const uint2* __restrict__ X8,
                                                   const int* __restrict__ offsets,
                                                   const int* __restrict__ ssrc,
                                                   const float* __restrict__ inv_deg,
                                                   uint4* __restrict__ A1q, int N) {
  int node = blockIdx.x * 4 + (threadIdx.x >> 6);
  if (node >= N) return;
  int lane = threadIdx.x & 63;
  int g = lane >> 4;
  int l = lane & 15;
  int s = offsets[node], e = offsets[node + 1];
  float a0=0.f,a1=0.f,a2=0.f,a3=0.f,a4=0.f,a5=0.f,a6=0.f,a7=0.f;
  int i = s;
  for (; i + 8 <= e; i += 8) {
    int sA = ssrc[i + g], sB = ssrc[i + 4 + g];
    uint2 u = X8[((size_t)(unsigned)sA << 4) + l];
    uint2 v = X8[((size_t)(unsigned)sB << 4) + l];
    f32x2 p, q;
    p = __builtin_amdgcn_cvt_pk_f32_fp8(u.x, false); q = __builtin_amdgcn_cvt_pk_f32_fp8(u.x, true);
    a0 += p[0]; a1 += p[1]; a2 += q[0]; a3 += q[1];
    p = __builtin_amdgcn_cvt_pk_f32_fp8(u.y, false); q = __builtin_amdgcn_cvt_pk_f32_fp8(u.y, true);
    a4 += p[0]; a5 += p[1]; a6 += q[0]; a7 += q[1];
    p = __builtin_amdgcn_cvt_pk_f32_fp8(v.x, false); q = __builtin_amdgcn_cvt_pk_f32_fp8(v.x, true);
    a0 += p[0]; a1 += p[1]; a2 += q[0]; a3 += q[1];
    p = __builtin_amdgcn_cvt_pk_f32_fp8(v.y, false); q = __builtin_amdgcn_cvt_pk_f32_fp8(v.y, true);
    a4 += p[0]; a5 += p[1]; a6 += q[0]; a7 += q[1];
  }
  for (; i < e; i += 4) {
    if (g < e - i) {
      uint2 u = X8[((size_t)(unsigned)ssrc[i + g] << 4) + l];
      f32x2 p, q;
      p = __builtin_amdgcn_cvt_pk_f32_fp8(u.x, false); q = __builtin_amdgcn_cvt_pk_f32_fp8(u.x, true);
      a0 += p[0]; a1 += p[1]; a2 += q[0]; a3 += q[1];
      p = __builtin_amdgcn_cvt_pk_f32_fp8(u.y, false); q = __builtin_amdgcn_cvt_pk_f32_fp8(u.y, true);
      a4 += p[0]; a5 += p[1]; a6 += q[0]; a7 += q[1];
    }
  }
  a0 += __shfl_xor(a0,16,64); a0 += __shfl_xor(a0,32,64);
  a1 += __shfl_xor(a1,16,64); a1 += __shfl_xor(a1,32,64);
  a2 += __shfl_xor(a2,16,64); a2 += __shfl_xor(a2,32,64);
  a3 += __shfl_xor(a3,16,64); a3 += __shfl_xor(a3,32,64);
  a4 += __shfl_xor(a4,16,64); a4 += __shfl_xor(a4,32,64);
  a5 += __shfl_xor(a5,16,64); a5 += __shfl_xor(a5,32,64);
  a6 += __shfl_xor(a6,16,64); a6 += __shfl_xor(a6,32,64);
  a7 += __shfl_xor(a7,16,64); a7 += __shfl_xor(a7,32,64);
  if (g == 0) {
    float id = inv_deg[node];
    A1q[((size_t)node << 5) + 16 + l] =
        make_uint4(pack2(a0 * id, a1 * id), pack2(a2 * id, a3 * id),
                   pack2(a4 * id, a5 * id), pack2(a6 * id, a7 * id));
  }
}

// ================= bf16 MFMA GEMM =================
// mode 0: out0 = bf16 relu(acc+bias) [M,256]
// mode 1: y==0 -> out0 bf16 [M,128] (utop); y==1 -> out1 fp8-e4m3 [M,128] (t2)
__global__ __launch_bounds__(256) void gemm_mfma(const short* __restrict__ A,
                                                 const short* __restrict__ Bp,
                                                 const float* __restrict__ bias,
                                                 void* __restrict__ out0,
                                                 void* __restrict__ out1,
                                                 int M_pad, int mode) {
  __shared__ __align__(16) short As[4096];
  __shared__ __align__(16) short Bs[4096];
  int tid = threadIdx.x;
  int w = tid >> 6;
  int lane = tid & 63;
  int wr = w >> 1;
  int wc = w & 1;
  int bm = blockIdx.x * 128;
  int bn = blockIdx.y * 128;

  f32x4 acc[4][4];
  #pragma unroll
  for (int i = 0; i < 4; ++i)
    #pragma unroll
    for (int j = 0; j < 4; ++j) acc[i][j] = (f32x4)(0.0f);

  for (int kb = 0; kb < 8; ++kb) {
    #pragma unroll
    for (int q = 0; q < 2; ++q) {
      int f = q * 4 + w;
      int row = bm + f * 16 + (lane & 15);
      const short* g = A + (size_t)row * 256 + kb * 32 + (lane >> 4) * 8;
      async_copy16(g, &As[f * 512]);
    }
    #pragma unroll
    for (int q = 0; q < 2; ++q) {
      int f = q * 4 + w;
      const short* g = Bp + ((size_t)(kb * 16 + (bn >> 4) + f) * 64 + lane) * 8;
      async_copy16(g, &Bs[f * 512]);
    }
    __syncthreads();

    bf16x8 af[4], bfr[4];
    #pragma unroll
    for (int i = 0; i < 4; ++i)
      af[i] = *(const bf16x8*)&As[(wr * 4 + i) * 512 + lane * 8];
    #pragma unroll
    for (int j = 0; j < 4; ++j)
      bfr[j] = *(const bf16x8*)&Bs[(wc * 4 + j) * 512 + lane * 8];

    #pragma unroll
    for (int i = 0; i < 4; ++i)
      #pragma unroll
      for (int j = 0; j < 4; ++j)
        acc[i][j] = __builtin_amdgcn_mfma_f32_16x16x32_bf16(af[i], bfr[j], acc[i][j], 0, 0, 0);
    __syncthreads();
  }

  int crow0 = (lane >> 4) * 4;
  int ccol = lane & 15;
  #pragma unroll
  for (int i = 0; i < 4; ++i) {
    #pragma unroll
    for (int j = 0; j < 4; ++j) {
      int col_loc = wc * 64 + j * 16 + ccol;
      int col = bn + col_loc;
      #pragma unroll
      for (int r = 0; r < 4; ++r) {
        int row = bm + wr * 64 + i * 16 + crow0 + r;
        float v = acc[i][j][r] + bias[col];
        if (mode == 0) {
          v = fmaxf(v, 0.0f);
          ((short*)out0)[(size_t)row * 256 + col] = bf16_rne(v);
        } else if (blockIdx.y == 0) {
          ((short*)out0)[(size_t)row * 128 + col_loc] = bf16_rne(v);
        } else {
          int pk = __builtin_amdgcn_cvt_pk_fp8_f32(v, v, 0, false);
          ((unsigned char*)out1)[(size_t)row * 128 + col_loc] = (unsigned char)(pk & 0xff);
        }
      }
    }
  }
}

// ================= fused final: quad-mode fp8 gather + bf16 utop + log_softmax =======
__global__ __launch_bounds__(256) void final_kernel(const uint4* __restrict__ utopq,
                                                    const uint2* __restrict__ T2,
                                                    const int* __restrict__ offsets,
                                                    const int* __restrict__ ssrc,
                                                    const float* __restrict__ inv_deg,
                                                    float4* __restrict__ out4, int N) {
  int node = blockIdx.x * 4 + (threadIdx.x >> 6);
  if (node >= N) return;
  int lane = threadIdx.x & 63;
  int g = lane >> 4;
  int l = lane & 15;
  int s = offsets[node], e = offsets[node + 1];
  float a0=0.f,a1=0.f,a2=0.f,a3=0.f,a4=0.f,a5=0.f,a6=0.f,a7=0.f;
  int i = s;
  for (; i + 8 <= e; i += 8) {
    int sA = ssrc[i + g], sB = ssrc[i + 4 + g];
    uint2 u = T2[((size_t)(unsigned)sA << 4) + l];
    uint2 v = T2[((size_t)(unsigned)sB << 4) + l];
    f32x2 p, q;
    p = __builtin_amdgcn_cvt_pk_f32_fp8(u.x, false); q = __builtin_amdgcn_cvt_pk_f32_fp8(u.x, true);
    a0 += p[0]; a1 += p[1]; a2 += q[0]; a3 += q[1];
    p = __builtin_amdgcn_cvt_pk_f32_fp8(u.y, false); q = __builtin_amdgcn_cvt_pk_f32_fp8(u.y, true);
    a4 += p[0]; a5 += p[1]; a6 += q[0]; a7 += q[1];
    p = __builtin_amdgcn_cvt_pk_f32_fp8(v.x, false); q = __builtin_amdgcn_cvt_pk_f32_fp8(v.x, true);
    a0 += p[0]; a1 += p[1]; a2 += q[0]; a3 += q[1];
    p = __builtin_amdgcn_cvt_pk_f32_fp8(v.y, false); q = __builtin_amdgcn_cvt_pk_f32_fp8(v.y, true);
    a4 += p[0]; a5 += p[1]; a6 += q[0]; a7 += q[1];
  }
  for (; i < e; i += 4) {
    if (g < e - i) {
      uint2 u = T2[((size_t)(unsigned)ssrc[i + g] << 4) + l];
      f32x2 p, q;
      p = __builtin_amdgcn_cvt_pk_f32_fp8(u.x, false); q = __builtin_amdgcn_cvt_pk_f32_fp8(u.x, true);
      a0 += p[0]; a1 += p[1]; a2 += q[0]; a3 += q[1];
      p = __builtin_amdgcn_cvt_pk_f32_fp8(u.y, false); q = __builtin_amdgcn_cvt_pk_f32_fp8(u.y, true);
      a4 += p[0]; a5 += p[1]; a6 += q[0]; a7 += q[1];
    }
  }
  a0 += __shfl_xor(a0,16,64); a0 += __shfl_xor(a0,32,64);
  a1 += __shfl_xor(a1,16,64); a1 += __shfl_xor(a1,32,64);
  a2 += __shfl_xor(a2,16,64); a2 += __shfl_xor(a2,32,64);
  a3 += __shfl_xor(a3,16,64); a3 += __shfl_xor(a3,32,64);
  a4 += __shfl_xor(a4,16,64); a4 += __shfl_xor(a4,32,64);
  a5 += __shfl_xor(a5,16,64); a5 += __shfl_xor(a5,32,64);
  a6 += __shfl_xor(a6,16,64); a6 += __shfl_xor(a6,32,64);
  a7 += __shfl_xor(a7,16,64); a7 += __shfl_xor(a7,32,64);
  if (g == 0) {
    float id = inv_deg[node];
    uint4 U = utopq[((size_t)node << 4) + l];
    float v0 = bf16lo(U.x) + a0 * id;
    float v1 = bf16hi(U.x) + a1 * id;
    float v2 = bf16lo(U.y) + a2 * id;
    float v3 = bf16hi(U.y) + a3 * id;
    float v4 = bf16lo(U.z) + a4 * id;
    float v5 = bf16hi(U.z) + a5 * id;
    float v6 = bf16lo(U.w) + a6 * id;
    float v7 = bf16hi(U.w) + a7 * id;
    float m = fmaxf(fmaxf(fmaxf(v0, v1), fmaxf(v2, v3)), fmaxf(fmaxf(v4, v5), fmaxf(v6, v7)));
    #pragma unroll
    for (int off = 1; off < 16; off <<= 1) m = fmaxf(m, __shfl_xor(m, off, 16));
    float su = expf(v0 - m) + expf(v1 - m) + expf(v2 - m) + expf(v3 - m) +
               expf(v4 - m) + expf(v5 - m) + expf(v6 - m) + expf(v7 - m);
    #pragma unroll
    for (int off = 1; off < 16; off <<= 1) su += __shfl_xor(su, off, 16);
    float ls = m + logf(su);
    out4[((size_t)node << 5) + l * 2]     = make_float4(v0 - ls, v1 - ls, v2 - ls, v3 - ls);
    out4[((size_t)node << 5) + l * 2 + 1] = make_float4(v4 - ls, v5 - ls, v6 - ls, v7 - ls);
  }
}

extern "C" void kernel_launch(void* const* d_in, const int* in_sizes, int n_in,
                              void* d_out, int out_size, void* d_ws, size_t ws_size,
                              hipStream_t stream) {
  const float* x        = (const float*)d_in[0];
  const int*   edge_src = (const int*)d_in[1];
  const int*   edge_dst = (const int*)d_in[2];
  const float* W1       = (const float*)d_in[3];
  const float* b1       = (const float*)d_in[4];
  const float* W2       = (const float*)d_in[5];
  const float* b2       = (const float*)d_in[6];
  float* out = (float*)d_out;

  const int D_IN = 128;
  const int N = in_sizes[0] / D_IN;
  const int E = in_sizes[1];
  const int M_pad = ((N + 127) / 128) * 128;

  const int SB = 1024;                   // edge-chunk blocks (must stay 1024 for part[] fold)
  const int EPB = (E + SB - 1) / SB;     // edges per chunk
  const int NB = (N + 127) >> 7;         // node buckets (128 nodes each)
  const int M = NB * SB;                 // hist matrix size; scan1 chunk t == bucket t
  const int sbl = (M + 1023) / 1024;     // == NB

  char* ws = (char*)d_ws;
  size_t p = 0;
  auto take = [&](size_t bytes) -> size_t {
    size_t r = p;
    p += (bytes + 255) & ~(size_t)255;
    return r;
  };
  size_t histT_off = take((size_t)M * 4);
  size_t excl_off  = take((size_t)(M + 1) * 4);
  size_t part_off  = take((size_t)1024 * 4);
  size_t bedge_off = take((size_t)E * 4);             // packed 4B/edge
  size_t offs_off  = take((size_t)(N + 1) * 4);
  size_t inv_off   = take((size_t)N * 4);
  size_t ssrc_off  = take((size_t)E * 4);
  size_t A1_off    = take((size_t)M_pad * 256 * 2);   // bf16 [x | agg1]
  size_t xf8_off   = take((size_t)M_pad * 128);       // fp8 x gather table
  size_t h_off     = take((size_t)M_pad * 256 * 2);   // bf16 h
  size_t B1p_off   = take((size_t)256 * 256 * 2);
  size_t B2p_off   = take((size_t)256 * 256 * 2);
  size_t bias2_off = take((size_t)256 * 4);
  size_t utop_off  = take((size_t)M_pad * 128 * 2);   // bf16
  size_t t2_off    = take((size_t)M_pad * 128);       // fp8
  (void)ws_size;

  int*   histT   = (int*)(ws + histT_off);
  int*   excl    = (int*)(ws + excl_off);
  int*   part    = (int*)(ws + part_off);
  unsigned* bedge = (unsigned*)(ws + bedge_off);
  int*   offsets = (int*)(ws + offs_off);
  float* inv_deg = (float*)(ws + inv_off);
  int*   ssrc    = (int*)(ws + ssrc_off);
  unsigned* A1u  = (unsigned*)(ws + A1_off);
  unsigned* xf8  = (unsigned*)(ws + xf8_off);
  short* h       = (short*)(ws + h_off);
  short* B1p     = (short*)(ws + B1p_off);
  short* B2p     = (short*)(ws + B2p_off);
  float* bias2   = (float*)(ws + bias2_off);
  short* utop    = (short*)(ws + utop_off);
  unsigned char* t2f8 = (unsigned char*)(ws + t2_off);

  // ---- CSR build ----
  bucket_hist<<<SB, 256, 0, stream>>>(edge_dst, E, EPB, histT, SB, NB);
  scan1_kernel<<<sbl, 1024, 0, stream>>>(histT, excl, part, M);
  scan2_kernel<<<1, 1024, 0, stream>>>(part, sbl);
  bucket_scatter<<<SB, 256, 0, stream>>>(edge_src, edge_dst, E, EPB, excl, part, SB, NB, bedge);
  build_csr<<<NB, 256, 0, stream>>>(bedge, excl, part, SB, NB, N, E, offsets, inv_deg, ssrc);

  // ---- fused prep: pack weights, bias2, convert x (bf16 + fp8 table) ----
  {
    int nquads = N * 32;
    int grid = 513 + (nquads + 255) / 256;
    prep_kernel<<<grid, 256, 0, stream>>>(W1, W2, b2, x, B1p, B2p, bias2, A1u, xf8, nquads);
  }

  // ---- layer 1 ----
  agg1_kernel<<<(N + 3) / 4, 256, 0, stream>>>((const uint2*)xf8, offsets, ssrc, inv_deg,
                                               (uint4*)A1u, N);
  {
    dim3 grid(M_pad / 128, 2);
    gemm_mfma<<<grid, 256, 0, stream>>>((const short*)A1u, B1p, b1, h, nullptr, M_pad, 0);
  }
  // ---- layer 2 (split: utop = bf16(h@W2_top + b2), t2 = fp8(h@W2_bot)) ----
  {
    dim3 grid(M_pad / 128, 2);
    gemm_mfma<<<grid, 256, 0, stream>>>(h, B2p, bias2, utop, t2f8, M_pad, 1);
  }
  // ---- fused aggregate + log_softmax ----
  final_kernel<<<(N + 3) / 4, 256, 0, stream>>>((const uint4*)utop, (const uint2*)t2f8,
                                                offsets, ssrc, inv_deg, (float4*)out, N);
}

// Round 8
// 228.598 us; speedup vs baseline: 3.1471x; 1.0361x over previous
//
#include <hip/hip_runtime.h>
#include <cstdint>
#include <cstddef>

typedef __attribute__((ext_vector_type(8))) short bf16x8;
typedef __attribute__((ext_vector_type(4))) float f32x4;
typedef __attribute__((ext_vector_type(2))) float f32x2;

__device__ inline short bf16_rne(float f) {
  unsigned u = __builtin_bit_cast(unsigned, f);
  u += 0x7fff + ((u >> 16) & 1);
  return (short)(u >> 16);
}

__device__ inline float bf16lo(unsigned v) { return __builtin_bit_cast(float, v << 16); }
__device__ inline float bf16hi(unsigned v) { return __builtin_bit_cast(float, v & 0xffff0000u); }

__device__ inline unsigned pack2(float a, float b) {
  return ((unsigned)(unsigned short)bf16_rne(a)) | (((unsigned)(unsigned short)bf16_rne(b)) << 16);
}

__device__ inline void async_copy16(const void* g, void* l) {
  __builtin_amdgcn_global_load_lds((const __attribute__((address_space(1))) void*)g,
                                   (__attribute__((address_space(3))) void*)l, 16, 0, 0);
}

// ================= CSR build: bucketed counting sort =================
// Buckets of 128 nodes (bucket = dst >> 7). NB buckets, SB=512 edge-chunk blocks.
// bedge packs (dst&127)<<24 | src  (src < 2^24).
// scan1 uses 512-thread blocks so scan-block t covers exactly histT row t
// (bucket t) -> part[t] is bucket t's total; scan3 stays folded into consumers.

// fused prep: bucket histogram + pack W1/W2 + bias2 + convert x (bf16 + fp8)
__global__ __launch_bounds__(256) void prep_kernel(const int* __restrict__ dst, int E, int EPB,
                                                   int* __restrict__ histT, int SB, int NB,
                                                   const float* __restrict__ W1,
                                                   const float* __restrict__ W2,
                                                   const float* __restrict__ b2,
                                                   const float* __restrict__ x,
                                                   short* __restrict__ B1p,
                                                   short* __restrict__ B2p,
                                                   float* __restrict__ bias2,
                                                   unsigned* __restrict__ A1u,
                                                   unsigned* __restrict__ xf8, int nquads) {
  __shared__ int h[512];
  int b = blockIdx.x;
  int tid = threadIdx.x;
  if (b < SB) {
    // ---- bucket histogram ----
    for (int t = tid; t < NB; t += 256) h[t] = 0;
    __syncthreads();
    int start = b * EPB, end = min(E, start + EPB);
    for (int i = start + tid; i < end; i += 256) atomicAdd(&h[((unsigned)dst[i]) >> 7], 1);
    __syncthreads();
    for (int t = tid; t < NB; t += 256) histT[t * SB + b] = h[t];
  } else if (b < SB + 512) {
    // ---- weight pack into frag-ordered bf16 ----
    int bb = b - SB;
    int mode = bb >> 8;
    int idx = (bb & 255) * 256 + tid;  // 65536 per weight
    int j = idx & 7;
    int L = (idx >> 3) & 63;
    int nt = (idx >> 9) & 15;
    int kb = idx >> 13;
    int k = kb * 32 + (L >> 4) * 8 + j;
    int n = nt * 16 + (L & 15);
    if (mode == 0) {
      B1p[idx] = bf16_rne(W1[(size_t)k * 256 + n]);
    } else {
      float v = (n < 128) ? W2[(size_t)k * 128 + n] : W2[(size_t)(256 + k) * 128 + (n - 128)];
      B2p[idx] = bf16_rne(v);
    }
  } else if (b == SB + 512) {
    int j = tid;
    bias2[j] = (j < 128) ? b2[j] : 0.0f;
  } else {
    // ---- convert x: bf16 left half of A1 + fp8 gather table ----
    int idx = (b - SB - 513) * 256 + tid;  // quad of 4 floats
    if (idx < nquads) {
      int n = idx >> 5, q = idx & 31;
      float4 v = ((const float4*)x)[idx];
      ((uint2*)A1u)[(size_t)n * 64 + q] = make_uint2(pack2(v.x, v.y), pack2(v.z, v.w));
      int pk = __builtin_amdgcn_cvt_pk_fp8_f32(v.x, v.y, 0, false);
      pk = __builtin_amdgcn_cvt_pk_fp8_f32(v.z, v.w, pk, true);
      xf8[(size_t)n * 32 + q] = (unsigned)pk;
    }
  }
}

// scan over M = NB*512 elements; block t == bucket t
__global__ __launch_bounds__(512) void scan1_kernel(const int* __restrict__ in,
                                                    int* __restrict__ outx,
                                                    int* __restrict__ part, int n) {
  __shared__ int buf[512];
  int tid = threadIdx.x;
  int i = blockIdx.x * 512 + tid;
  int v = (i < n) ? in[i] : 0;
  buf[tid] = v;
  __syncthreads();
  #pragma unroll
  for (int off = 1; off < 512; off <<= 1) {
    int t = (tid >= off) ? buf[tid - off] : 0;
    __syncthreads();
    buf[tid] += t;
    __syncthreads();
  }
  if (i < n) outx[i] = buf[tid] - v;
  if (tid == 511) part[blockIdx.x] = buf[511];
}

// scan up to 1024 partials with one block (in place, exclusive)
__global__ __launch_bounds__(1024) void scan2_kernel(int* __restrict__ part, int B) {
  __shared__ int buf[1024];
  int tid = threadIdx.x;
  int v = (tid < B) ? part[tid] : 0;
  buf[tid] = v;
  __syncthreads();
  #pragma unroll
  for (int off = 1; off < 1024; off <<= 1) {
    int t = (tid >= off) ? buf[tid - off] : 0;
    __syncthreads();
    buf[tid] += t;
    __syncthreads();
  }
  if (tid < B) part[tid] = buf[tid] - v;
}

// scatter packed (dst&127,src) into bucket-grouped order
__global__ __launch_bounds__(256) void bucket_scatter(const int* __restrict__ src,
                                                      const int* __restrict__ dst, int E, int EPB,
                                                      const int* __restrict__ excl,
                                                      const int* __restrict__ part, int SB, int NB,
                                                      unsigned* __restrict__ bedge) {
  __shared__ int cur[512];
  int tid = threadIdx.x;
  for (int t = tid; t < NB; t += 256) cur[t] = excl[t * SB + blockIdx.x] + part[t];
  __syncthreads();
  int start = blockIdx.x * EPB, end = min(E, start + EPB);
  for (int i = start + tid; i < end; i += 256) {
    unsigned d = (unsigned)dst[i];
    int p = atomicAdd(&cur[d >> 7], 1);
    bedge[p] = ((d & 127u) << 24) | (unsigned)src[i];
  }
}

// per-bucket CSR finalize (128 nodes per bucket)
__global__ __launch_bounds__(256) void build_csr(const unsigned* __restrict__ bedge,
                                                 const int* __restrict__ excl,
                                                 const int* __restrict__ part, int SB, int NB,
                                                 int N, int E,
                                                 int* __restrict__ offsets,
                                                 float* __restrict__ inv_deg,
                                                 int* __restrict__ ssrc) {
  __shared__ int buf[128];
  int b = blockIdx.x, tid = threadIdx.x;
  int estart = excl[b * SB] + part[b];
  int eend = (b == NB - 1) ? E : (excl[(b + 1) * SB] + part[b + 1]);
  if (tid < 128) buf[tid] = 0;
  __syncthreads();
  for (int i = estart + tid; i < eend; i += 256) atomicAdd(&buf[bedge[i] >> 24], 1);
  __syncthreads();
  int cnt = (tid < 128) ? buf[tid] : 0;
  #pragma unroll
  for (int off = 1; off < 128; off <<= 1) {
    int t = (tid >= off && tid < 128) ? buf[tid - off] : 0;
    __syncthreads();
    if (tid < 128) buf[tid] += t;
    __syncthreads();
  }
  if (tid < 128) {
    int excl_l = buf[tid] - cnt;
    int node = (b << 7) + tid;
    if (node < N) {
      offsets[node] = estart + excl_l;
      inv_deg[node] = 1.0f / fmaxf((float)cnt, 1.0f);
    }
    if (node == N) offsets[N] = E;
    buf[tid] = estart + excl_l;  // cursor
  }
  __syncthreads();
  for (int i = estart + tid; i < eend; i += 256) {
    unsigned e2 = bedge[i];
    int p = atomicAdd(&buf[e2 >> 24], 1);
    ssrc[p] = (int)(e2 & 0xFFFFFFu);
  }
}

// ================= quad-mode fp8 gathers =================
// table row = 128 B = 16 uint2; 16 lanes per edge, lane l holds dims l*8..l*8+7.
#define CVT8(U, A0, A1, A2, A3, A4, A5, A6, A7)                                        \
  {                                                                                    \
    f32x2 p_, q_;                                                                      \
    p_ = __builtin_amdgcn_cvt_pk_f32_fp8((U).x, false);                                \
    q_ = __builtin_amdgcn_cvt_pk_f32_fp8((U).x, true);                                 \
    A0 += p_[0]; A1 += p_[1]; A2 += q_[0]; A3 += q_[1];                                \
    p_ = __builtin_amdgcn_cvt_pk_f32_fp8((U).y, false);                                \
    q_ = __builtin_amdgcn_cvt_pk_f32_fp8((U).y, true);                                 \
    A4 += p_[0]; A5 += p_[1]; A6 += q_[0]; A7 += q_[1];                                \
  }

// layer-1 aggregation: wave per node, writes bf16 into A1 right half
__global__ __launch_bounds__(256) void agg1_kernel(const uint2* __restrict__ X8,
                                                   const int* __restrict__ offsets,
                                                   const int* __restrict__ ssrc,
                                                   const float* __restrict__ inv_deg,
                                                   uint4* __restrict__ A1q, int N) {
  int node = blockIdx.x * 4 + (threadIdx.x >> 6);
  if (node >= N) return;
  int lane = threadIdx.x & 63;
  int g = lane >> 4;
  int l = lane & 15;
  int s = offsets[node], e = offsets[node + 1];
  float a0=0.f,a1=0.f,a2=0.f,a3=0.f,a4=0.f,a5=0.f,a6=0.f,a7=0.f;
  int i = s;
  for (; i + 16 <= e; i += 16) {
    int sA = ssrc[i + g], sB = ssrc[i + 4 + g];
    int sC = ssrc[i + 8 + g], sD = ssrc[i + 12 + g];
    uint2 u = X8[((size_t)(unsigned)sA << 4) + l];
    uint2 v = X8[((size_t)(unsigned)sB << 4) + l];
    uint2 w = X8[((size_t)(unsigned)sC << 4) + l];
    uint2 z = X8[((size_t)(unsigned)sD << 4) + l];
    CVT8(u, a0,a1,a2,a3,a4,a5,a6,a7);
    CVT8(v, a0,a1,a2,a3,a4,a5,a6,a7);
    CVT8(w, a0,a1,a2,a3,a4,a5,a6,a7);
    CVT8(z, a0,a1,a2,a3,a4,a5,a6,a7);
  }
  for (; i < e; i += 4) {
    if (g < e - i) {
      uint2 u = X8[((size_t)(unsigned)ssrc[i + g] << 4) + l];
      CVT8(u, a0,a1,a2,a3,a4,a5,a6,a7);
    }
  }
  a0 += __shfl_xor(a0,16,64); a0 += __shfl_xor(a0,32,64);
  a1 += __shfl_xor(a1,16,64); a1 += __shfl_xor(a1,32,64);
  a2 += __shfl_xor(a2,16,64); a2 += __shfl_xor(a2,32,64);
  a3 += __shfl_xor(a3,16,64); a3 += __shfl_xor(a3,32,64);
  a4 += __shfl_xor(a4,16,64); a4 += __shfl_xor(a4,32,64);
  a5 += __shfl_xor(a5,16,64); a5 += __shfl_xor(a5,32,64);
  a6 += __shfl_xor(a6,16,64); a6 += __shfl_xor(a6,32,64);
  a7 += __shfl_xor(a7,16,64); a7 += __shfl_xor(a7,32,64);
  if (g == 0) {
    float id = inv_deg[node];
    A1q[((size_t)node << 5) + 16 + l] =
        make_uint4(pack2(a0 * id, a1 * id), pack2(a2 * id, a3 * id),
                   pack2(a4 * id, a5 * id), pack2(a6 * id, a7 * id));
  }
}

// ================= bf16 MFMA GEMM =================
// mode 0: out0 = bf16 relu(acc+bias) [M,256]
// mode 1: y==0 -> out0 bf16 [M,128] (utop); y==1 -> out1 fp8-e4m3 [M,128] (t2)
__global__ __launch_bounds__(256) void gemm_mfma(const short* __restrict__ A,
                                                 const short* __restrict__ Bp,
                                                 const float* __restrict__ bias,
                                                 void* __restrict__ out0,
                                                 void* __restrict__ out1,
                                                 int M_pad, int mode) {
  __shared__ __align__(16) short As[4096];
  __shared__ __align__(16) short Bs[4096];
  int tid = threadIdx.x;
  int w = tid >> 6;
  int lane = tid & 63;
  int wr = w >> 1;
  int wc = w & 1;
  int bm = blockIdx.x * 128;
  int bn = blockIdx.y * 128;

  f32x4 acc[4][4];
  #pragma unroll
  for (int i = 0; i < 4; ++i)
    #pragma unroll
    for (int j = 0; j < 4; ++j) acc[i][j] = (f32x4)(0.0f);

  for (int kb = 0; kb < 8; ++kb) {
    #pragma unroll
    for (int q = 0; q < 2; ++q) {
      int f = q * 4 + w;
      int row = bm + f * 16 + (lane & 15);
      const short* g = A + (size_t)row * 256 + kb * 32 + (lane >> 4) * 8;
      async_copy16(g, &As[f * 512]);
    }
    #pragma unroll
    for (int q = 0; q < 2; ++q) {
      int f = q * 4 + w;
      const short* g = Bp + ((size_t)(kb * 16 + (bn >> 4) + f) * 64 + lane) * 8;
      async_copy16(g, &Bs[f * 512]);
    }
    __syncthreads();

    bf16x8 af[4], bfr[4];
    #pragma unroll
    for (int i = 0; i < 4; ++i)
      af[i] = *(const bf16x8*)&As[(wr * 4 + i) * 512 + lane * 8];
    #pragma unroll
    for (int j = 0; j < 4; ++j)
      bfr[j] = *(const bf16x8*)&Bs[(wc * 4 + j) * 512 + lane * 8];

    #pragma unroll
    for (int i = 0; i < 4; ++i)
      #pragma unroll
      for (int j = 0; j < 4; ++j)
        acc[i][j] = __builtin_amdgcn_mfma_f32_16x16x32_bf16(af[i], bfr[j], acc[i][j], 0, 0, 0);
    __syncthreads();
  }

  int crow0 = (lane >> 4) * 4;
  int ccol = lane & 15;
  #pragma unroll
  for (int i = 0; i < 4; ++i) {
    #pragma unroll
    for (int j = 0; j < 4; ++j) {
      int col_loc = wc * 64 + j * 16 + ccol;
      int col = bn + col_loc;
      #pragma unroll
      for (int r = 0; r < 4; ++r) {
        int row = bm + wr * 64 + i * 16 + crow0 + r;
        float v = acc[i][j][r] + bias[col];
        if (mode == 0) {
          v = fmaxf(v, 0.0f);
          ((short*)out0)[(size_t)row * 256 + col] = bf16_rne(v);
        } else if (blockIdx.y == 0) {
          ((short*)out0)[(size_t)row * 128 + col_loc] = bf16_rne(v);
        } else {
          int pk = __builtin_amdgcn_cvt_pk_fp8_f32(v, v, 0, false);
          ((unsigned char*)out1)[(size_t)row * 128 + col_loc] = (unsigned char)(pk & 0xff);
        }
      }
    }
  }
}

// ================= fused final: quad-mode fp8 gather + bf16 utop + log_softmax =======
__global__ __launch_bounds__(256) void final_kernel(const uint4* __restrict__ utopq,
                                                    const uint2* __restrict__ T2,
                                                    const int* __restrict__ offsets,
                                                    const int* __restrict__ ssrc,
                                                    const float* __restrict__ inv_deg,
                                                    float4* __restrict__ out4, int N) {
  int node = blockIdx.x * 4 + (threadIdx.x >> 6);
  if (node >= N) return;
  int lane = threadIdx.x & 63;
  int g = lane >> 4;
  int l = lane & 15;
  int s = offsets[node], e = offsets[node + 1];
  float a0=0.f,a1=0.f,a2=0.f,a3=0.f,a4=0.f,a5=0.f,a6=0.f,a7=0.f;
  int i = s;
  for (; i + 16 <= e; i += 16) {
    int sA = ssrc[i + g], sB = ssrc[i + 4 + g];
    int sC = ssrc[i + 8 + g], sD = ssrc[i + 12 + g];
    uint2 u = T2[((size_t)(unsigned)sA << 4) + l];
    uint2 v = T2[((size_t)(unsigned)sB << 4) + l];
    uint2 w = T2[((size_t)(unsigned)sC << 4) + l];
    uint2 z = T2[((size_t)(unsigned)sD << 4) + l];
    CVT8(u, a0,a1,a2,a3,a4,a5,a6,a7);
    CVT8(v, a0,a1,a2,a3,a4,a5,a6,a7);
    CVT8(w, a0,a1,a2,a3,a4,a5,a6,a7);
    CVT8(z, a0,a1,a2,a3,a4,a5,a6,a7);
  }
  for (; i < e; i += 4) {
    if (g < e - i) {
      uint2 u = T2[((size_t)(unsigned)ssrc[i + g] << 4) + l];
      CVT8(u, a0,a1,a2,a3,a4,a5,a6,a7);
    }
  }
  a0 += __shfl_xor(a0,16,64); a0 += __shfl_xor(a0,32,64);
  a1 += __shfl_xor(a1,16,64); a1 += __shfl_xor(a1,32,64);
  a2 += __shfl_xor(a2,16,64); a2 += __shfl_xor(a2,32,64);
  a3 += __shfl_xor(a3,16,64); a3 += __shfl_xor(a3,32,64);
  a4 += __shfl_xor(a4,16,64); a4 += __shfl_xor(a4,32,64);
  a5 += __shfl_xor(a5,16,64); a5 += __shfl_xor(a5,32,64);
  a6 += __shfl_xor(a6,16,64); a6 += __shfl_xor(a6,32,64);
  a7 += __shfl_xor(a7,16,64); a7 += __shfl_xor(a7,32,64);
  if (g == 0) {
    float id = inv_deg[node];
    uint4 U = utopq[((size_t)node << 4) + l];
    float v0 = bf16lo(U.x) + a0 * id;
    float v1 = bf16hi(U.x) + a1 * id;
    float v2 = bf16lo(U.y) + a2 * id;
    float v3 = bf16hi(U.y) + a3 * id;
    float v4 = bf16lo(U.z) + a4 * id;
    float v5 = bf16hi(U.z) + a5 * id;
    float v6 = bf16lo(U.w) + a6 * id;
    float v7 = bf16hi(U.w) + a7 * id;
    float m = fmaxf(fmaxf(fmaxf(v0, v1), fmaxf(v2, v3)), fmaxf(fmaxf(v4, v5), fmaxf(v6, v7)));
    #pragma unroll
    for (int off = 1; off < 16; off <<= 1) m = fmaxf(m, __shfl_xor(m, off, 16));
    float su = expf(v0 - m) + expf(v1 - m) + expf(v2 - m) + expf(v3 - m) +
               expf(v4 - m) + expf(v5 - m) + expf(v6 - m) + expf(v7 - m);
    #pragma unroll
    for (int off = 1; off < 16; off <<= 1) su += __shfl_xor(su, off, 16);
    float ls = m + logf(su);
    out4[((size_t)node << 5) + l * 2]     = make_float4(v0 - ls, v1 - ls, v2 - ls, v3 - ls);
    out4[((size_t)node << 5) + l * 2 + 1] = make_float4(v4 - ls, v5 - ls, v6 - ls, v7 - ls);
  }
}

extern "C" void kernel_launch(void* const* d_in, const int* in_sizes, int n_in,
                              void* d_out, int out_size, void* d_ws, size_t ws_size,
                              hipStream_t stream) {
  const float* x        = (const float*)d_in[0];
  const int*   edge_src = (const int*)d_in[1];
  const int*   edge_dst = (const int*)d_in[2];
  const float* W1       = (const float*)d_in[3];
  const float* b1       = (const float*)d_in[4];
  const float* W2       = (const float*)d_in[5];
  const float* b2       = (const float*)d_in[6];
  float* out = (float*)d_out;

  const int D_IN = 128;
  const int N = in_sizes[0] / D_IN;
  const int E = in_sizes[1];
  const int M_pad = ((N + 127) / 128) * 128;

  const int SB = 512;                    // edge-chunk blocks == scan1 block width
  const int EPB = (E + SB - 1) / SB;     // edges per chunk
  const int NB = (N + 127) >> 7;         // node buckets (128 nodes each)
  const int M = NB * SB;                 // hist matrix; scan1 block t == bucket t

  char* ws = (char*)d_ws;
  size_t p = 0;
  auto take = [&](size_t bytes) -> size_t {
    size_t r = p;
    p += (bytes + 255) & ~(size_t)255;
    return r;
  };
  size_t histT_off = take((size_t)M * 4);
  size_t excl_off  = take((size_t)(M + 1) * 4);
  size_t part_off  = take((size_t)1024 * 4);
  size_t bedge_off = take((size_t)E * 4);             // packed 4B/edge
  size_t offs_off  = take((size_t)(N + 1) * 4);
  size_t inv_off   = take((size_t)N * 4);
  size_t ssrc_off  = take((size_t)E * 4);
  size_t A1_off    = take((size_t)M_pad * 256 * 2);   // bf16 [x | agg1]
  size_t xf8_off   = take((size_t)M_pad * 128);       // fp8 x gather table
  size_t h_off     = take((size_t)M_pad * 256 * 2);   // bf16 h
  size_t B1p_off   = take((size_t)256 * 256 * 2);
  size_t B2p_off   = take((size_t)256 * 256 * 2);
  size_t bias2_off = take((size_t)256 * 4);
  size_t utop_off  = take((size_t)M_pad * 128 * 2);   // bf16
  size_t t2_off    = take((size_t)M_pad * 128);       // fp8
  (void)ws_size;

  int*   histT   = (int*)(ws + histT_off);
  int*   excl    = (int*)(ws + excl_off);
  int*   part    = (int*)(ws + part_off);
  unsigned* bedge = (unsigned*)(ws + bedge_off);
  int*   offsets = (int*)(ws + offs_off);
  float* inv_deg = (float*)(ws + inv_off);
  int*   ssrc    = (int*)(ws + ssrc_off);
  unsigned* A1u  = (unsigned*)(ws + A1_off);
  unsigned* xf8  = (unsigned*)(ws + xf8_off);
  short* h       = (short*)(ws + h_off);
  short* B1p     = (short*)(ws + B1p_off);
  short* B2p     = (short*)(ws + B2p_off);
  float* bias2   = (float*)(ws + bias2_off);
  short* utop    = (short*)(ws + utop_off);
  unsigned char* t2f8 = (unsigned char*)(ws + t2_off);

  // ---- fused prep (hist + weight pack + bias2 + x convert) ----
  {
    int nquads = N * 32;
    int grid = SB + 513 + (nquads + 255) / 256;
    prep_kernel<<<grid, 256, 0, stream>>>(edge_dst, E, EPB, histT, SB, NB,
                                          W1, W2, b2, x, B1p, B2p, bias2, A1u, xf8, nquads);
  }
  // ---- CSR build ----
  scan1_kernel<<<NB, 512, 0, stream>>>(histT, excl, part, M);
  scan2_kernel<<<1, 1024, 0, stream>>>(part, NB);
  bucket_scatter<<<SB, 256, 0, stream>>>(edge_src, edge_dst, E, EPB, excl, part, SB, NB, bedge);
  build_csr<<<NB, 256, 0, stream>>>(bedge, excl, part, SB, NB, N, E, offsets, inv_deg, ssrc);

  // ---- layer 1 ----
  agg1_kernel<<<(N + 3) / 4, 256, 0, stream>>>((const uint2*)xf8, offsets, ssrc, inv_deg,
                                               (uint4*)A1u, N);
  {
    dim3 grid(M_pad / 128, 2);
    gemm_mfma<<<grid, 256, 0, stream>>>((const short*)A1u, B1p, b1, h, nullptr, M_pad, 0);
  }
  // ---- layer 2 (split: utop = bf16(h@W2_top + b2), t2 = fp8(h@W2_bot)) ----
  {
    dim3 grid(M_pad / 128, 2);
    gemm_mfma<<<grid, 256, 0, stream>>>(h, B2p, bias2, utop, t2f8, M_pad, 1);
  }
  // ---- fused aggregate + log_softmax ----
  final_kernel<<<(N + 3) / 4, 256, 0, stream>>>((const uint4*)utop, (const uint2*)t2f8,
                                                offsets, ssrc, inv_deg, (float4*)out, N);
}